// Round 3
// baseline (575.960 us; speedup 1.0000x reference)
//
#include <hip/hip_runtime.h>
#include <hip/hip_bf16.h>
#include <math.h>

typedef __attribute__((ext_vector_type(8))) short short8;
typedef __attribute__((ext_vector_type(4))) float floatx4;
typedef unsigned short u16;
typedef unsigned int u32;

// ---------- bf16 helpers ----------
__device__ __forceinline__ u16 f2b(float f) {
  union { float f; u32 i; } v; v.f = f;
  u32 i = v.i;
  return (u16)((i + 0x7fffu + ((i >> 16) & 1u)) >> 16);  // RNE
}

// ---------- async global->LDS (16B/lane) ----------
#define GLD16(gp, lp)                                                          \
  __builtin_amdgcn_global_load_lds(                                            \
      (__attribute__((address_space(1))) u32*)(gp),                            \
      (__attribute__((address_space(3))) u32*)(lp), 16, 0, 0)

// ---------- constants ----------
#define T_TOK 4096
#define DDIM 1024
#define FDIM 2048
#define NEXP 8
// merged capacity: routed padded-to-256 (<=9984 worst case) + 4096 shared
#define CAP_ROWS 14080
#define CAP_MBLK 55   // CAP_ROWS/256

// ---------- fallback: ws too small -> sentinel 1e6 (distinguishable) ----------
__global__ void fallback_k(float* out, int n) {
  int i = blockIdx.x * 256 + threadIdx.x;
  if (i < n) out[i] = 1.0e6f;
}

// ---------- router + x cvt fused: LDS-staged Wg, 16 tokens/block, f32 math ----
// Also converts x (f32) -> xb (bf16) for the rows this block owns, reusing the
// same global reads. counts/rowtok are pre-initialized via hipMemsetAsync.
__global__ __launch_bounds__(256) void router_k(const float* __restrict__ x,
                                                const float* __restrict__ Wg,
                                                u16* __restrict__ xb,
                                                int* topi, float* topw, int* counts) {
  __shared__ float wgl[NEXP * DDIM];  // 32 KB, [e][d]
  const int tid = threadIdx.x;
#pragma unroll
  for (int k = 0; k < (NEXP * DDIM) / 256; k++) {
    int i = tid + k * 256;          // coalesced flat read of Wg [d][e]
    wgl[(i & 7) * DDIM + (i >> 3)] = Wg[i];
  }
  __syncthreads();
  const int wave = tid >> 6, lane = tid & 63;
  for (int j = 0; j < 4; j++) {
    int t = blockIdx.x * 16 + wave * 4 + j;
    const float* xr = x + (size_t)t * DDIM;
    u16* xbr = xb + (size_t)t * DDIM;
    float p[NEXP];
#pragma unroll
    for (int e = 0; e < NEXP; e++) p[e] = 0.f;
#pragma unroll
    for (int i = 0; i < 4; i++) {
      int d0 = i * 256 + lane * 4;
      float4 xv = *(const float4*)(xr + d0);
      union { u16 h[4]; uint2 u; } o;
      o.h[0] = f2b(xv.x); o.h[1] = f2b(xv.y); o.h[2] = f2b(xv.z); o.h[3] = f2b(xv.w);
      *(uint2*)(xbr + d0) = o.u;
#pragma unroll
      for (int e = 0; e < NEXP; e++) {
        float4 wv = *(const float4*)(wgl + e * DDIM + d0);
        p[e] += xv.x * wv.x + xv.y * wv.y + xv.z * wv.z + xv.w * wv.w;
      }
    }
#pragma unroll
    for (int off = 32; off > 0; off >>= 1)
#pragma unroll
      for (int e = 0; e < NEXP; e++) p[e] += __shfl_xor(p[e], off);
    if (lane == 0) {
      int i0 = 0; float l0 = p[0];
      for (int e = 1; e < NEXP; e++) if (p[e] > l0) { l0 = p[e]; i0 = e; }
      int i1 = (i0 == 0) ? 1 : 0; float l1 = p[i1];
      for (int e = 0; e < NEXP; e++) if (e != i0 && p[e] > l1) { l1 = p[e]; i1 = e; }
      float e1 = expf(l1 - l0);
      float s = 1.0f + e1;
      topi[t * 2] = i0; topi[t * 2 + 1] = i1;
      topw[t * 2] = 1.0f / s; topw[t * 2 + 1] = e1 / s;
      atomicAdd(&counts[i0], 1); atomicAdd(&counts[i1], 1);
    }
  }
}

// ---------- scan: serial 9-segment prefix (8 routed pad-256 + shared 4096) ----------
// meta[0] = total rows, meta[1] = shared segment base
__global__ void scan_k(const int* counts, int* cursor, int* blk_e, int* meta) {
  __shared__ int soff[NEXP + 1];
  const int tid = threadIdx.x;  // 64 threads
  if (tid == 0) {
    int off = 0;
    for (int e = 0; e < NEXP; e++) {
      soff[e] = off;
      int c = counts[e]; if (c < 0) c = 0; if (c > 4096) c = 4096;
      off += ((c + 255) >> 8) << 8;
    }
    if (off > CAP_ROWS - 4096) off = CAP_ROWS - 4096;
    soff[NEXP] = off;
    meta[1] = off;
    meta[0] = off + 4096;
  }
  __syncthreads();
  if (tid < NEXP) cursor[tid] = soff[tid];
  if (tid < CAP_MBLK) {
    int r = tid << 8;
    int e;
    if (r >= soff[NEXP]) e = NEXP;   // shared expert segment
    else {
      e = 0;
      for (int k = 0; k < NEXP; k++) if (r >= soff[k + 1]) e = k + 1;
      if (e > NEXP - 1) e = NEXP - 1;
    }
    blk_e[tid] = e;
  }
}

// ---------- assign: routed slots + shared segment fill ----------
__global__ void assign_k(const int* topi, const float* topw, int* cursor,
                         const int* meta, int* rowtok, float* rww) {
  int i = blockIdx.x * 256 + threadIdx.x;  // 12288 threads
  if (i < T_TOK * 2) {
    int e = topi[i]; if (e < 0) e = 0; if (e >= NEXP) e = NEXP - 1;
    int r = atomicAdd(&cursor[e], 1);
    if (r < 0) r = 0; if (r >= CAP_ROWS) r = CAP_ROWS - 1;
    rowtok[r] = i >> 1;
    rww[r] = topw[i];
  } else {
    int t = i - T_TOK * 2;            // 0..4095
    int r = meta[1] + t;
    if (r >= CAP_ROWS) r = CAP_ROWS - 1;
    rowtok[r] = t;
    rww[r] = 1.0f;
  }
}

// ---------- transpose+convert, two sources merged on blockIdx.z ----------
// z < zSplit: srcA expert z; z >= zSplit: srcB expert (z - zSplit)
__global__ void transpose_cvt2_k(const float* __restrict__ srcA,
                                 const float* __restrict__ srcB, int zSplit,
                                 u16* __restrict__ dst, int R, int C) {
  __shared__ float tile[32][33];
  int z = blockIdx.z;
  const float* src = (z < zSplit) ? srcA + (size_t)z * R * C
                                  : srcB + (size_t)(z - zSplit) * R * C;
  u16* d = dst + (size_t)z * R * C;
  int c0 = blockIdx.x * 32, r0 = blockIdx.y * 32;
#pragma unroll
  for (int i = 0; i < 4; i++)
    tile[threadIdx.y + i * 8][threadIdx.x] =
        src[(size_t)(r0 + threadIdx.y + i * 8) * C + c0 + threadIdx.x];
  __syncthreads();
#pragma unroll
  for (int i = 0; i < 4; i++)
    d[(size_t)(c0 + threadIdx.y + i * 8) * R + r0 + threadIdx.x] =
        f2b(tile[threadIdx.x][threadIdx.y + i * 8]);
}

// ---------- 256x256 BK=64 8-wave grouped GEMM, T3-minimum 2-phase ----------
// Round-2 post-mortem: 48 ds_read_b128/K-tile/wave (2x redundant) + 9 barriers
// serialized LDS (4608cy) against MFMA (2483cy) -> MfmaUtil 17.5%. This round:
// each fragment read ONCE (24 reads/K-tile), ONE barrier + one vmcnt(0) drain
// per K-tile (T3-minimum recipe: proven 655-792 TF at 256^2/K=1024 grouped).
// Per tile: STAGE(next) -> halfK0{12 reads+32 MFMA} -> halfK1 -> vmcnt(0),bar.
// MODE 0: gelu -> bf16 store to C16
// MODE 2: atomic f32: Cf[rowtok[row]*N+col] += rww[row]*v  (skip rowtok<0)
template <int MODE>
__global__ __launch_bounds__(512, 2) void gemm256(
    const u16* __restrict__ A, const u16* __restrict__ Bt,
    u16* __restrict__ C16, float* __restrict__ Cf,
    int N, int K, const int* __restrict__ blk_e, const int* __restrict__ meta,
    size_t bstride, const int* __restrict__ gatherA,
    const int* __restrict__ rowtok, const float* __restrict__ rww) {
  // ---- bijective XCD-chunked swizzle of flattened block id (m204 formula) ----
  const int nwg = gridDim.x * gridDim.y;
  const int bid = blockIdx.y * gridDim.x + blockIdx.x;
  const int q = nwg >> 3, r8 = nwg & 7;
  const int xcd = bid & 7, idx = bid >> 3;
  const int swz = (xcd < r8) ? xcd * (q + 1) + idx
                             : r8 * (q + 1) + (xcd - r8) * q + idx;
  const int bx = swz % gridDim.x, by = swz / gridDim.x;

  const int m0 = by * 256, n0 = bx * 256;
  if (m0 >= meta[0]) return;
  Bt += (size_t)blk_e[by] * bstride;

  __shared__ u16 As0[256 * 64];   // 32 KiB each, 128 KiB total
  __shared__ u16 Bs0[256 * 64];
  __shared__ u16 As1[256 * 64];
  __shared__ u16 Bs1[256 * 64];

  const int tid = threadIdx.x;
  const int wave = tid >> 6, lane = tid & 63;
  const int wm = wave >> 2, wn = wave & 3;   // 2 x 4 wave grid
  const int fr = lane & 15, hi = lane >> 4;

  // ---- staging sources: chunk c = i*512+tid covers physical 16B slot (r, c&7)
  // of the [256][64] tile; it fetches LOGICAL slot (c&7)^(r&7)  (XOR swizzle on
  // the global side because global_load_lds writes LDS linearly).
  const u16* asrc[4];
  const u16* bsrc[4];
#pragma unroll
  for (int i = 0; i < 4; i++) {
    int c = i * 512 + tid;
    int r = c >> 3;
    int sl = (c & 7) ^ (r & 7);
    int ga = m0 + r;
    if (gatherA) { int t2 = gatherA[ga]; ga = (t2 < 0 || t2 >= T_TOK) ? 0 : t2; }
    asrc[i] = A + (size_t)ga * K + sl * 8;
    bsrc[i] = Bt + (size_t)(n0 + r) * K + sl * 8;
  }

#define STAGE(kt, AL, BL)                                                      \
  do {                                                                         \
    const int k0_ = (kt) << 6;                                                 \
    _Pragma("unroll")                                                          \
    for (int i_ = 0; i_ < 4; i_++)                                             \
      GLD16(asrc[i_] + k0_, (AL) + i_ * 4096 + wave * 512);                    \
    _Pragma("unroll")                                                          \
    for (int i_ = 0; i_ < 4; i_++)                                             \
      GLD16(bsrc[i_] + k0_, (BL) + i_ * 4096 + wave * 512);                    \
  } while (0)

  // per-lane ds_read col offsets; fragment row r has r&7 == fr&7, so the
  // swizzled slot is a per-(lane,k) constant and fragment addrs are base+imm.
  int co[2];
#pragma unroll
  for (int k = 0; k < 2; k++)
    co[k] = fr * 64 + (((k << 2) + hi) ^ (fr & 7)) * 8;
  const int sA = wm * 8192;   // wm*128 rows * 64
  const int sB = wn * 4096;   // wn*64  rows * 64

  floatx4 acc[8][4];
#pragma unroll
  for (int mi = 0; mi < 8; mi++)
#pragma unroll
    for (int ni = 0; ni < 4; ni++) acc[mi][ni] = (floatx4){0.f, 0.f, 0.f, 0.f};

  // half-K pass: read each fragment once (8 A + 4 B b128), 32 MFMA cluster
#define HALFK(AL, BL, kk)                                                      \
  do {                                                                         \
    short8 aF[8], bF[4];                                                       \
    _Pragma("unroll")                                                          \
    for (int mi = 0; mi < 8; mi++)                                             \
      aF[mi] = *(const short8*)((AL) + sA + mi * 1024 + co[kk]);               \
    _Pragma("unroll")                                                          \
    for (int ni = 0; ni < 4; ni++)                                             \
      bF[ni] = *(const short8*)((BL) + sB + ni * 1024 + co[kk]);               \
    __builtin_amdgcn_s_setprio(1);                                             \
    _Pragma("unroll")                                                          \
    for (int mi = 0; mi < 8; mi++)                                             \
      _Pragma("unroll")                                                        \
      for (int ni = 0; ni < 4; ni++)                                           \
        acc[mi][ni] = __builtin_amdgcn_mfma_f32_16x16x32_bf16(                 \
            aF[mi], bF[ni], acc[mi][ni], 0, 0, 0);                             \
    __builtin_amdgcn_s_setprio(0);                                             \
  } while (0)

  const int NT = K >> 6;  // 16 or 32 here: always even, >= 2
  STAGE(0, As0, Bs0);
  asm volatile("s_waitcnt vmcnt(0)" ::: "memory");
  __builtin_amdgcn_s_barrier();
  for (int t = 0; t < NT; t += 2) {
    STAGE(t + 1, As1, Bs1);          // prefetch issue BEFORE compute (T14)
    HALFK(As0, Bs0, 0);
    HALFK(As0, Bs0, 1);
    asm volatile("s_waitcnt vmcnt(0)" ::: "memory");  // t+1 landed (hidden)
    __builtin_amdgcn_s_barrier();
    if (t + 2 < NT) STAGE(t + 2, As0, Bs0);
    HALFK(As1, Bs1, 0);
    HALFK(As1, Bs1, 1);
    asm volatile("s_waitcnt vmcnt(0)" ::: "memory");
    __builtin_amdgcn_s_barrier();
  }
#undef STAGE
#undef HALFK

  // ---- epilogue: C/D layout col=lane&15, row=(lane>>4)*4+reg ----
#pragma unroll
  for (int mi = 0; mi < 8; mi++)
#pragma unroll
    for (int r = 0; r < 4; r++) {
      int row = m0 + wm * 128 + mi * 16 + hi * 4 + r;
      int tok = 0; float w = 0.f;
      if (MODE == 2) {
        tok = rowtok[row];
        if (tok >= 0) w = rww[row];
      }
#pragma unroll
      for (int ni = 0; ni < 4; ni++) {
        int col = n0 + wn * 64 + ni * 16 + fr;
        float v = acc[mi][ni][r];
        if (MODE == 0) {
          v = 0.5f * v * (1.0f + erff(v * 0.70710678118654752f));
          C16[(size_t)row * N + col] = f2b(v);
        } else {
          if (tok >= 0) atomicAdd(Cf + (size_t)tok * N + col, w * v);
        }
      }
    }
}

extern "C" void kernel_launch(void* const* d_in, const int* in_sizes, int n_in,
                              void* d_out, int out_size, void* d_ws, size_t ws_size,
                              hipStream_t stream) {
  const float* x  = (const float*)d_in[0];
  const float* Wg = (const float*)d_in[1];
  const float* Wu = (const float*)d_in[2];
  const float* Wd = (const float*)d_in[3];
  const float* W1 = (const float*)d_in[4];
  const float* W2 = (const float*)d_in[5];
  float* out = (float*)d_out;

  // ---- workspace layout (~104 MB; Wt reused up->down) ----
  char* ws = (char*)d_ws;
  size_t off = 0;
  auto alloc = [&](size_t b) -> void* {
    void* p = ws + off; off += (b + 255) & ~(size_t)255; return p;
  };
  int*   counts = (int*)alloc(NEXP * 4);
  int*   cursor = (int*)alloc(NEXP * 4);
  int*   meta   = (int*)alloc(2 * 4);
  int*   blk_e  = (int*)alloc(CAP_MBLK * 4);
  int*   topi   = (int*)alloc(T_TOK * 2 * 4);
  float* topw   = (float*)alloc(T_TOK * 2 * 4);
  int*   rowtok = (int*)alloc(CAP_ROWS * 4);
  float* rww    = (float*)alloc(CAP_ROWS * 4);
  u16*   Xb     = (u16*)alloc((size_t)T_TOK * DDIM * 2);                 // 8.4 MB
  u16*   Wt     = (u16*)alloc((size_t)(NEXP + 1) * FDIM * DDIM * 2);     // 37.7 MB
  u16*   Hrg    = (u16*)alloc((size_t)CAP_ROWS * FDIM * 2);              // 57.7 MB
  (void)n_in; (void)in_sizes; (void)out_size;

  if (ws_size < off) {
    fallback_k<<<(T_TOK * DDIM + 255) / 256, 256, 0, stream>>>(out, T_TOK * DDIM);
    return;
  }

  dim3 tb(32, 8);
  // ---- routing (f32 logits: selection must match reference) ----
  hipMemsetAsync(counts, 0, NEXP * 4, stream);
  hipMemsetAsync(rowtok, 0xFF, (size_t)CAP_ROWS * 4, stream);  // -1 pattern
  hipMemsetAsync(out, 0, (size_t)T_TOK * DDIM * 4, stream);
  router_k<<<T_TOK / 16, 256, 0, stream>>>(x, Wg, Xb, topi, topw, counts);
  scan_k<<<1, 64, 0, stream>>>(counts, cursor, blk_e, meta);
  assign_k<<<(T_TOK * 2 + T_TOK) / 256, 256, 0, stream>>>(topi, topw, cursor, meta,
                                                          rowtok, rww);
  // ---- phase up: Hrg = gelu(gather(x) @ Wu[e])  (expert 8 = shared W1) ----
  transpose_cvt2_k<<<dim3(FDIM / 32, DDIM / 32, NEXP + 1), tb, 0, stream>>>(
      Wu, W1, NEXP, Wt, DDIM, FDIM);
  gemm256<0><<<dim3(FDIM / 256, CAP_MBLK), 512, 0, stream>>>(
      Xb, Wt, Hrg, nullptr, FDIM, DDIM, blk_e, meta, (size_t)FDIM * DDIM,
      rowtok, nullptr, nullptr);
  // ---- phase down: out += rww * (Hrg @ Wd[e])  (expert 8 = shared W2, w=1) ----
  transpose_cvt2_k<<<dim3(DDIM / 32, FDIM / 32, NEXP + 1), tb, 0, stream>>>(
      Wd, W2, NEXP, Wt, FDIM, DDIM);
  gemm256<2><<<dim3(DDIM / 256, CAP_MBLK), 512, 0, stream>>>(
      Hrg, Wt, nullptr, out, DDIM, FDIM, blk_e, meta, (size_t)DDIM * FDIM,
      nullptr, rowtok, rww);
}

// Round 4
// 505.115 us; speedup vs baseline: 1.1403x; 1.1403x over previous
//
#include <hip/hip_runtime.h>
#include <hip/hip_bf16.h>
#include <math.h>

typedef __attribute__((ext_vector_type(8))) short short8;
typedef __attribute__((ext_vector_type(4))) float floatx4;
typedef unsigned short u16;
typedef unsigned int u32;

// ---------- bf16 helpers ----------
__device__ __forceinline__ u16 f2b(float f) {
  union { float f; u32 i; } v; v.f = f;
  u32 i = v.i;
  return (u16)((i + 0x7fffu + ((i >> 16) & 1u)) >> 16);  // RNE
}

// ---------- async global->LDS (16B/lane) ----------
#define GLD16(gp, lp)                                                          \
  __builtin_amdgcn_global_load_lds(                                            \
      (__attribute__((address_space(1))) u32*)(gp),                            \
      (__attribute__((address_space(3))) u32*)(lp), 16, 0, 0)

// ---------- constants ----------
#define T_TOK 4096
#define DDIM 1024
#define FDIM 2048
#define NEXP 8
// merged capacity: routed padded-to-256 (<=9984 worst case) + 4096 shared
#define CAP_ROWS 14080
#define CAP_MBLK 55   // CAP_ROWS/256

// ---------- fallback: ws too small -> sentinel 1e6 (distinguishable) ----------
__global__ void fallback_k(float* out, int n) {
  int i = blockIdx.x * 256 + threadIdx.x;
  if (i < n) out[i] = 1.0e6f;
}

// ---------- router + x cvt fused: LDS-staged Wg, 16 tokens/block, f32 math ----
__global__ __launch_bounds__(256) void router_k(const float* __restrict__ x,
                                                const float* __restrict__ Wg,
                                                u16* __restrict__ xb,
                                                int* topi, float* topw, int* counts) {
  __shared__ float wgl[NEXP * DDIM];  // 32 KB, [e][d]
  const int tid = threadIdx.x;
#pragma unroll
  for (int k = 0; k < (NEXP * DDIM) / 256; k++) {
    int i = tid + k * 256;          // coalesced flat read of Wg [d][e]
    wgl[(i & 7) * DDIM + (i >> 3)] = Wg[i];
  }
  __syncthreads();
  const int wave = tid >> 6, lane = tid & 63;
  for (int j = 0; j < 4; j++) {
    int t = blockIdx.x * 16 + wave * 4 + j;
    const float* xr = x + (size_t)t * DDIM;
    u16* xbr = xb + (size_t)t * DDIM;
    float p[NEXP];
#pragma unroll
    for (int e = 0; e < NEXP; e++) p[e] = 0.f;
#pragma unroll
    for (int i = 0; i < 4; i++) {
      int d0 = i * 256 + lane * 4;
      float4 xv = *(const float4*)(xr + d0);
      union { u16 h[4]; uint2 u; } o;
      o.h[0] = f2b(xv.x); o.h[1] = f2b(xv.y); o.h[2] = f2b(xv.z); o.h[3] = f2b(xv.w);
      *(uint2*)(xbr + d0) = o.u;
#pragma unroll
      for (int e = 0; e < NEXP; e++) {
        float4 wv = *(const float4*)(wgl + e * DDIM + d0);
        p[e] += xv.x * wv.x + xv.y * wv.y + xv.z * wv.z + xv.w * wv.w;
      }
    }
#pragma unroll
    for (int off = 32; off > 0; off >>= 1)
#pragma unroll
      for (int e = 0; e < NEXP; e++) p[e] += __shfl_xor(p[e], off);
    if (lane == 0) {
      int i0 = 0; float l0 = p[0];
      for (int e = 1; e < NEXP; e++) if (p[e] > l0) { l0 = p[e]; i0 = e; }
      int i1 = (i0 == 0) ? 1 : 0; float l1 = p[i1];
      for (int e = 0; e < NEXP; e++) if (e != i0 && p[e] > l1) { l1 = p[e]; i1 = e; }
      float e1 = expf(l1 - l0);
      float s = 1.0f + e1;
      topi[t * 2] = i0; topi[t * 2 + 1] = i1;
      topw[t * 2] = 1.0f / s; topw[t * 2 + 1] = e1 / s;
      atomicAdd(&counts[i0], 1); atomicAdd(&counts[i1], 1);
    }
  }
}

// ---------- scan: serial 9-segment prefix (8 routed pad-256 + shared 4096) ----------
__global__ void scan_k(const int* counts, int* cursor, int* blk_e, int* meta) {
  __shared__ int soff[NEXP + 1];
  const int tid = threadIdx.x;  // 64 threads
  if (tid == 0) {
    int off = 0;
    for (int e = 0; e < NEXP; e++) {
      soff[e] = off;
      int c = counts[e]; if (c < 0) c = 0; if (c > 4096) c = 4096;
      off += ((c + 255) >> 8) << 8;
    }
    if (off > CAP_ROWS - 4096) off = CAP_ROWS - 4096;
    soff[NEXP] = off;
    meta[1] = off;
    meta[0] = off + 4096;
  }
  __syncthreads();
  if (tid < NEXP) cursor[tid] = soff[tid];
  if (tid < CAP_MBLK) {
    int r = tid << 8;
    int e;
    if (r >= soff[NEXP]) e = NEXP;   // shared expert segment
    else {
      e = 0;
      for (int k = 0; k < NEXP; k++) if (r >= soff[k + 1]) e = k + 1;
      if (e > NEXP - 1) e = NEXP - 1;
    }
    blk_e[tid] = e;
  }
}

// ---------- assign: routed slots + shared segment fill ----------
__global__ void assign_k(const int* topi, const float* topw, int* cursor,
                         const int* meta, int* rowtok, float* rww) {
  int i = blockIdx.x * 256 + threadIdx.x;  // 12288 threads
  if (i < T_TOK * 2) {
    int e = topi[i]; if (e < 0) e = 0; if (e >= NEXP) e = NEXP - 1;
    int r = atomicAdd(&cursor[e], 1);
    if (r < 0) r = 0; if (r >= CAP_ROWS) r = CAP_ROWS - 1;
    rowtok[r] = i >> 1;
    rww[r] = topw[i];
  } else {
    int t = i - T_TOK * 2;            // 0..4095
    int r = meta[1] + t;
    if (r >= CAP_ROWS) r = CAP_ROWS - 1;
    rowtok[r] = t;
    rww[r] = 1.0f;
  }
}

// ---------- transpose+convert, two sources merged on blockIdx.z ----------
__global__ void transpose_cvt2_k(const float* __restrict__ srcA,
                                 const float* __restrict__ srcB, int zSplit,
                                 u16* __restrict__ dst, int R, int C) {
  __shared__ float tile[32][33];
  int z = blockIdx.z;
  const float* src = (z < zSplit) ? srcA + (size_t)z * R * C
                                  : srcB + (size_t)(z - zSplit) * R * C;
  u16* d = dst + (size_t)z * R * C;
  int c0 = blockIdx.x * 32, r0 = blockIdx.y * 32;
#pragma unroll
  for (int i = 0; i < 4; i++)
    tile[threadIdx.y + i * 8][threadIdx.x] =
        src[(size_t)(r0 + threadIdx.y + i * 8) * C + c0 + threadIdx.x];
  __syncthreads();
#pragma unroll
  for (int i = 0; i < 4; i++)
    d[(size_t)(c0 + threadIdx.y + i * 8) * R + r0 + threadIdx.x] =
        f2b(tile[threadIdx.x][threadIdx.y + i * 8]);
}

// ---------- 256x256 BK=64 8-wave grouped GEMM, m201-style 8-phase ----------
// Derived schedule (per iteration = 2 K-tiles t->buf0, t+1->buf1):
//  reads once/fragment: ph1 aF(mh0)+bF01, ph2 bF23, ph3 aF(mh1), ph4 none
//  (B dead after ph2, A after ph3 -> per-phase stage slots open up)
//  MFMA quadrant order (0,0),(0,1),(1,1),(1,0): bF regs reused, no re-reads
//  stages: ph1/ph2 (t+1).A -> buf1 | ph3/ph4 (t+2).B -> buf0
//          ph5/ph6 (t+2).A -> buf0 | ph7/ph8 (t+3).B -> buf1
//  counted vmcnt(4) at ph4 (retires (t+1) A+B) and ph8 (retires (t+2) A+B);
//  loads fly 4-6 phases. Never drain in main loop (T3+T4); T5 setprio on MFMA.
// MODE 0: gelu -> bf16 store to C16
// MODE 2: atomic f32: Cf[rowtok[row]*N+col] += rww[row]*v  (skip rowtok<0)
template <int MODE>
__global__ __launch_bounds__(512, 2) void gemm256(
    const u16* __restrict__ A, const u16* __restrict__ Bt,
    u16* __restrict__ C16, float* __restrict__ Cf,
    int N, int K, const int* __restrict__ blk_e, const int* __restrict__ meta,
    size_t bstride, const int* __restrict__ gatherA,
    const int* __restrict__ rowtok, const float* __restrict__ rww) {
  // ---- bijective XCD-chunked swizzle (m204 formula) ----
  const int nwg = gridDim.x * gridDim.y;
  const int bid = blockIdx.y * gridDim.x + blockIdx.x;
  const int q = nwg >> 3, r8 = nwg & 7;
  const int xcd = bid & 7, idx = bid >> 3;
  const int swz = (xcd < r8) ? xcd * (q + 1) + idx
                             : r8 * (q + 1) + (xcd - r8) * q + idx;
  const int bx = swz % gridDim.x, by = swz / gridDim.x;

  const int m0 = by * 256, n0 = bx * 256;
  if (m0 >= meta[0]) return;
  Bt += (size_t)blk_e[by] * bstride;

  __shared__ u16 sm[4][16384];  // A0,B0,A1,B1 : 32 KiB each = 128 KiB
  u16* A0l = &sm[0][0]; u16* B0l = &sm[1][0];
  u16* A1l = &sm[2][0]; u16* B1l = &sm[3][0];

  const int tid = threadIdx.x;
  const int wave = tid >> 6, lane = tid & 63;
  const int wm = wave >> 2, wn = wave & 3;   // 2 x 4 wave grid
  const int fr = lane & 15, hi = lane >> 4;

  // staging sources: unit (h,u): physical slot c=u*512+tid of half h covers
  // row h*128+(c>>3); it fetches LOGICAL 16B slot (c&7)^((c>>3)&7) (XOR swizzle
  // on the global side because global_load_lds writes LDS linearly).
  const u16* aps[2][2];
  const u16* bps[2][2];
#pragma unroll
  for (int h = 0; h < 2; h++)
#pragma unroll
    for (int u = 0; u < 2; u++) {
      int c = u * 512 + tid;
      int rh = c >> 3;
      int sl = (c & 7) ^ (rh & 7);
      int row = h * 128 + rh;
      int ga = m0 + row;
      if (gatherA) { int t2 = gatherA[ga]; ga = (t2 < 0 || t2 >= T_TOK) ? 0 : t2; }
      aps[h][u] = A + (size_t)ga * K + sl * 8;
      bps[h][u] = Bt + (size_t)(n0 + row) * K + sl * 8;
    }

  // stage half h of a [256][64] tile into LDS buffer DL at k-offset KO (2 loads)
#define STG(ps, h, DL, KO)                                                     \
  do {                                                                         \
    GLD16(ps[h][0] + (KO), (DL) + (h) * 8192 + wave * 512);                    \
    GLD16(ps[h][1] + (KO), (DL) + (h) * 8192 + 4096 + wave * 512);             \
  } while (0)

  // per-lane ds_read col offsets (swizzled): fragment row r has r&7 == fr&7
  int co[2];
#pragma unroll
  for (int k = 0; k < 2; k++)
    co[k] = fr * 64 + (((k << 2) + hi) ^ (fr & 7)) * 8;
  const int sA = wm * 8192;   // wm*128 rows * 64
  const int sB = wn * 4096;   // wn*64  rows * 64

  floatx4 acc[8][4];
#pragma unroll
  for (int mi = 0; mi < 8; mi++)
#pragma unroll
    for (int ni = 0; ni < 4; ni++) acc[mi][ni] = (floatx4){0.f, 0.f, 0.f, 0.f};

  short8 aF[4][2], bF[4][2];

#define RD_A(AL, mh)                                                           \
  do {                                                                         \
    _Pragma("unroll")                                                          \
    for (int mi = 0; mi < 4; mi++)                                             \
      _Pragma("unroll")                                                        \
      for (int k = 0; k < 2; k++)                                              \
        aF[mi][k] =                                                            \
            *(const short8*)((AL) + sA + ((mh) * 4 + mi) * 1024 + co[k]);      \
  } while (0)
#define RD_B(BL, n0i)                                                          \
  do {                                                                         \
    _Pragma("unroll")                                                          \
    for (int ni = 0; ni < 2; ni++)                                             \
      _Pragma("unroll")                                                        \
      for (int k = 0; k < 2; k++)                                              \
        bF[(n0i) + ni][k] =                                                    \
            *(const short8*)((BL) + sB + ((n0i) + ni) * 1024 + co[k]);         \
  } while (0)

#define MM(mh, nh)                                                             \
  do {                                                                         \
    __builtin_amdgcn_s_setprio(1);                                             \
    _Pragma("unroll")                                                          \
    for (int mi = 0; mi < 4; mi++)                                             \
      _Pragma("unroll")                                                        \
      for (int ni = 0; ni < 2; ni++)                                           \
        _Pragma("unroll")                                                      \
        for (int k = 0; k < 2; k++)                                            \
          acc[(mh) * 4 + mi][(nh) * 2 + ni] =                                  \
              __builtin_amdgcn_mfma_f32_16x16x32_bf16(                         \
                  aF[mi][k], bF[(nh) * 2 + ni][k],                             \
                  acc[(mh) * 4 + mi][(nh) * 2 + ni], 0, 0, 0);                 \
    __builtin_amdgcn_s_setprio(0);                                             \
  } while (0)

#define BAR() __builtin_amdgcn_s_barrier()
#define LGK0() asm volatile("s_waitcnt lgkmcnt(0)" ::: "memory")
#define VMC(n) asm volatile("s_waitcnt vmcnt(" #n ")" ::: "memory")

  // one iteration = 2 K-tiles (t in buf0, t+1 in buf1); STGE=1: prefetch t+2/t+3
#define ITER(STGE, k1, k2, k3)                                                 \
  do {                                                                         \
    /* ph1 */                                                                  \
    RD_A(A0l, 0); RD_B(B0l, 0);                                                \
    STG(aps, 0, A1l, (k1));                                                    \
    BAR(); LGK0(); MM(0, 0); BAR();                                            \
    /* ph2 */                                                                  \
    RD_B(B0l, 2);                                                              \
    STG(aps, 1, A1l, (k1));                                                    \
    BAR(); LGK0(); MM(0, 1); BAR();                                            \
    /* ph3 */                                                                  \
    RD_A(A0l, 1);                                                              \
    if (STGE) STG(bps, 0, B0l, (k2));                                          \
    BAR(); LGK0(); MM(1, 1); BAR();                                            \
    /* ph4 */                                                                  \
    if (STGE) { STG(bps, 1, B0l, (k2)); VMC(4); } else { VMC(0); }             \
    BAR(); LGK0(); MM(1, 0); BAR();                                            \
    /* ph5 */                                                                  \
    RD_A(A1l, 0); RD_B(B1l, 0);                                                \
    if (STGE) STG(aps, 0, A0l, (k2));                                          \
    BAR(); LGK0(); MM(0, 0); BAR();                                            \
    /* ph6 */                                                                  \
    RD_B(B1l, 2);                                                              \
    if (STGE) STG(aps, 1, A0l, (k2));                                          \
    BAR(); LGK0(); MM(0, 1); BAR();                                            \
    /* ph7 */                                                                  \
    RD_A(A1l, 1);                                                              \
    if (STGE) STG(bps, 0, B1l, (k3));                                          \
    BAR(); LGK0(); MM(1, 1); BAR();                                            \
    /* ph8 */                                                                  \
    if (STGE) { STG(bps, 1, B1l, (k3)); VMC(4); }                              \
    BAR(); LGK0(); MM(1, 0); BAR();                                            \
  } while (0)

  const int NT = K >> 6;   // 16 (up) or 32 (down); even
  const int NI = NT >> 1;  // >= 8

  // prologue: tile0 A+B (8 loads), tile1 B (4 loads); keep tile1-B in flight
  STG(aps, 0, A0l, 0); STG(aps, 1, A0l, 0);
  STG(bps, 0, B0l, 0); STG(bps, 1, B0l, 0);
  STG(bps, 0, B1l, 64); STG(bps, 1, B1l, 64);
  VMC(4);
  BAR();

  for (int i = 0; i < NI - 1; ++i) {
    const int t = i << 1;
    ITER(1, (t + 1) << 6, (t + 2) << 6, (t + 3) << 6);
  }
  { // final iteration: only (NT-1).A stages remain (ph1/ph2); drain at ph4
    const int t = (NI - 1) << 1;
    ITER(0, (t + 1) << 6, 0, 0);
  }
#undef ITER
#undef STG
#undef RD_A
#undef RD_B
#undef MM
#undef BAR
#undef LGK0
#undef VMC

  // ---- epilogue: C/D layout col=lane&15, row=(lane>>4)*4+reg ----
#pragma unroll
  for (int mi = 0; mi < 8; mi++)
#pragma unroll
    for (int r = 0; r < 4; r++) {
      int row = m0 + wm * 128 + mi * 16 + hi * 4 + r;
      int tok = 0; float w = 0.f;
      if (MODE == 2) {
        tok = rowtok[row];
        if (tok >= 0) w = rww[row];
      }
#pragma unroll
      for (int ni = 0; ni < 4; ni++) {
        int col = n0 + wn * 64 + ni * 16 + fr;
        float v = acc[mi][ni][r];
        if (MODE == 0) {
          v = 0.5f * v * (1.0f + erff(v * 0.70710678118654752f));
          C16[(size_t)row * N + col] = f2b(v);
        } else {
          if (tok >= 0) atomicAdd(Cf + (size_t)tok * N + col, w * v);
        }
      }
    }
}

extern "C" void kernel_launch(void* const* d_in, const int* in_sizes, int n_in,
                              void* d_out, int out_size, void* d_ws, size_t ws_size,
                              hipStream_t stream) {
  const float* x  = (const float*)d_in[0];
  const float* Wg = (const float*)d_in[1];
  const float* Wu = (const float*)d_in[2];
  const float* Wd = (const float*)d_in[3];
  const float* W1 = (const float*)d_in[4];
  const float* W2 = (const float*)d_in[5];
  float* out = (float*)d_out;

  // ---- workspace layout (~104 MB; Wt reused up->down) ----
  char* ws = (char*)d_ws;
  size_t off = 0;
  auto alloc = [&](size_t b) -> void* {
    void* p = ws + off; off += (b + 255) & ~(size_t)255; return p;
  };
  int*   counts = (int*)alloc(NEXP * 4);
  int*   cursor = (int*)alloc(NEXP * 4);
  int*   meta   = (int*)alloc(2 * 4);
  int*   blk_e  = (int*)alloc(CAP_MBLK * 4);
  int*   topi   = (int*)alloc(T_TOK * 2 * 4);
  float* topw   = (float*)alloc(T_TOK * 2 * 4);
  int*   rowtok = (int*)alloc(CAP_ROWS * 4);
  float* rww    = (float*)alloc(CAP_ROWS * 4);
  u16*   Xb     = (u16*)alloc((size_t)T_TOK * DDIM * 2);                 // 8.4 MB
  u16*   Wt     = (u16*)alloc((size_t)(NEXP + 1) * FDIM * DDIM * 2);     // 37.7 MB
  u16*   Hrg    = (u16*)alloc((size_t)CAP_ROWS * FDIM * 2);              // 57.7 MB
  (void)n_in; (void)in_sizes; (void)out_size;

  if (ws_size < off) {
    fallback_k<<<(T_TOK * DDIM + 255) / 256, 256, 0, stream>>>(out, T_TOK * DDIM);
    return;
  }

  dim3 tb(32, 8);
  // ---- routing (f32 logits: selection must match reference) ----
  hipMemsetAsync(counts, 0, NEXP * 4, stream);
  hipMemsetAsync(rowtok, 0xFF, (size_t)CAP_ROWS * 4, stream);  // -1 pattern
  hipMemsetAsync(out, 0, (size_t)T_TOK * DDIM * 4, stream);
  router_k<<<T_TOK / 16, 256, 0, stream>>>(x, Wg, Xb, topi, topw, counts);
  scan_k<<<1, 64, 0, stream>>>(counts, cursor, blk_e, meta);
  assign_k<<<(T_TOK * 2 + T_TOK) / 256, 256, 0, stream>>>(topi, topw, cursor, meta,
                                                          rowtok, rww);
  // ---- phase up: Hrg = gelu(gather(x) @ Wu[e])  (expert 8 = shared W1) ----
  transpose_cvt2_k<<<dim3(FDIM / 32, DDIM / 32, NEXP + 1), tb, 0, stream>>>(
      Wu, W1, NEXP, Wt, DDIM, FDIM);
  gemm256<0><<<dim3(FDIM / 256, CAP_MBLK), 512, 0, stream>>>(
      Xb, Wt, Hrg, nullptr, FDIM, DDIM, blk_e, meta, (size_t)FDIM * DDIM,
      rowtok, nullptr, nullptr);
  // ---- phase down: out += rww * (Hrg @ Wd[e])  (expert 8 = shared W2, w=1) ----
  transpose_cvt2_k<<<dim3(DDIM / 32, FDIM / 32, NEXP + 1), tb, 0, stream>>>(
      Wd, W2, NEXP, Wt, FDIM, DDIM);
  gemm256<2><<<dim3(DDIM / 256, CAP_MBLK), 512, 0, stream>>>(
      Hrg, Wt, nullptr, out, DDIM, FDIM, blk_e, meta, (size_t)DDIM * FDIM,
      nullptr, rowtok, rww);
}

// Round 5
// 502.738 us; speedup vs baseline: 1.1456x; 1.0047x over previous
//
#include <hip/hip_runtime.h>
#include <hip/hip_bf16.h>
#include <math.h>

typedef __attribute__((ext_vector_type(8))) short short8;
typedef __attribute__((ext_vector_type(4))) float floatx4;
typedef unsigned short u16;
typedef unsigned int u32;

// ---------- bf16 helpers ----------
__device__ __forceinline__ u16 f2b(float f) {
  union { float f; u32 i; } v; v.f = f;
  u32 i = v.i;
  return (u16)((i + 0x7fffu + ((i >> 16) & 1u)) >> 16);  // RNE
}

// ---------- async global->LDS (16B/lane) ----------
#define GLD16(gp, lp)                                                          \
  __builtin_amdgcn_global_load_lds(                                            \
      (__attribute__((address_space(1))) u32*)(gp),                            \
      (__attribute__((address_space(3))) u32*)(lp), 16, 0, 0)

// ---------- constants ----------
#define T_TOK 4096
#define DDIM 1024
#define FDIM 2048
#define NEXP 8
// merged capacity: routed padded-to-256 (<=9984 worst case) + 4096 shared
#define CAP_ROWS 14080
#define CAP_MBLK 55   // CAP_ROWS/256

// ---------- fallback: ws too small -> sentinel 1e6 (distinguishable) ----------
__global__ void fallback_k(float* out, int n) {
  int i = blockIdx.x * 256 + threadIdx.x;
  if (i < n) out[i] = 1.0e6f;
}

// ---------- router + x cvt fused: 1 token/wave, 4 blocks/CU (TLP) ----------
// Round-4 analysis: 256 blocks x 4 serial tokens/wave = 1 wave/SIMD, pure
// latency-bound. Now 1024 blocks x 4 waves x 1 token: 16 waves/CU.
// f32 math and identical reduce -> expert selection matches reference.
__global__ __launch_bounds__(256) void router_k(const float* __restrict__ x,
                                                const float* __restrict__ Wg,
                                                u16* __restrict__ xb,
                                                int* topi, float* topw, int* counts) {
  __shared__ float wgl[NEXP * DDIM];  // 32 KB, [e][d]
  const int tid = threadIdx.x;
#pragma unroll
  for (int k = 0; k < (NEXP * DDIM) / 256; k++) {
    int i = tid + k * 256;          // coalesced flat read of Wg [d][e]
    wgl[(i & 7) * DDIM + (i >> 3)] = Wg[i];
  }
  __syncthreads();
  const int wave = tid >> 6, lane = tid & 63;
  const int t = blockIdx.x * 4 + wave;
  const float* xr = x + (size_t)t * DDIM;
  u16* xbr = xb + (size_t)t * DDIM;
  float p[NEXP];
#pragma unroll
  for (int e = 0; e < NEXP; e++) p[e] = 0.f;
#pragma unroll
  for (int i = 0; i < 4; i++) {
    int d0 = i * 256 + lane * 4;
    float4 xv = *(const float4*)(xr + d0);
    union { u16 h[4]; uint2 u; } o;
    o.h[0] = f2b(xv.x); o.h[1] = f2b(xv.y); o.h[2] = f2b(xv.z); o.h[3] = f2b(xv.w);
    *(uint2*)(xbr + d0) = o.u;
#pragma unroll
    for (int e = 0; e < NEXP; e++) {
      float4 wv = *(const float4*)(wgl + e * DDIM + d0);
      p[e] += xv.x * wv.x + xv.y * wv.y + xv.z * wv.z + xv.w * wv.w;
    }
  }
#pragma unroll
  for (int off = 32; off > 0; off >>= 1)
#pragma unroll
    for (int e = 0; e < NEXP; e++) p[e] += __shfl_xor(p[e], off);
  if (lane == 0) {
    int i0 = 0; float l0 = p[0];
    for (int e = 1; e < NEXP; e++) if (p[e] > l0) { l0 = p[e]; i0 = e; }
    int i1 = (i0 == 0) ? 1 : 0; float l1 = p[i1];
    for (int e = 0; e < NEXP; e++) if (e != i0 && p[e] > l1) { l1 = p[e]; i1 = e; }
    float e1 = expf(l1 - l0);
    float s = 1.0f + e1;
    topi[t * 2] = i0; topi[t * 2 + 1] = i1;
    topw[t * 2] = 1.0f / s; topw[t * 2 + 1] = e1 / s;
    atomicAdd(&counts[i0], 1); atomicAdd(&counts[i1], 1);
  }
}

// ---------- scan: serial 9-segment prefix (8 routed pad-256 + shared 4096) ----------
__global__ void scan_k(const int* counts, int* cursor, int* blk_e, int* meta) {
  __shared__ int soff[NEXP + 1];
  const int tid = threadIdx.x;  // 64 threads
  if (tid == 0) {
    int off = 0;
    for (int e = 0; e < NEXP; e++) {
      soff[e] = off;
      int c = counts[e]; if (c < 0) c = 0; if (c > 4096) c = 4096;
      off += ((c + 255) >> 8) << 8;
    }
    if (off > CAP_ROWS - 4096) off = CAP_ROWS - 4096;
    soff[NEXP] = off;
    meta[1] = off;
    meta[0] = off + 4096;
  }
  __syncthreads();
  if (tid < NEXP) cursor[tid] = soff[tid];
  if (tid < CAP_MBLK) {
    int r = tid << 8;
    int e;
    if (r >= soff[NEXP]) e = NEXP;   // shared expert segment
    else {
      e = 0;
      for (int k = 0; k < NEXP; k++) if (r >= soff[k + 1]) e = k + 1;
      if (e > NEXP - 1) e = NEXP - 1;
    }
    blk_e[tid] = e;
  }
}

// ---------- assign: routed slots + shared segment fill ----------
__global__ void assign_k(const int* topi, const float* topw, int* cursor,
                         const int* meta, int* rowtok, float* rww) {
  int i = blockIdx.x * 256 + threadIdx.x;  // 12288 threads
  if (i < T_TOK * 2) {
    int e = topi[i]; if (e < 0) e = 0; if (e >= NEXP) e = NEXP - 1;
    int r = atomicAdd(&cursor[e], 1);
    if (r < 0) r = 0; if (r >= CAP_ROWS) r = CAP_ROWS - 1;
    rowtok[r] = i >> 1;
    rww[r] = topw[i];
  } else {
    int t = i - T_TOK * 2;            // 0..4095
    int r = meta[1] + t;
    if (r >= CAP_ROWS) r = CAP_ROWS - 1;
    rowtok[r] = t;
    rww[r] = 1.0f;
  }
}

// ---------- transpose+convert v2: 64x64 tiles, 16B coalesced BOTH sides -----
// Old 32x32 version wrote 64B per 32-lane row (scalar u16) -> ~2x HBM waste.
// Here: float4 reads, LDS [64][65] (2-way bank aliasing = free both sides),
// uint4 (8x bf16) contiguous writes. z < zSplit: srcA[z]; else srcB[z-zSplit].
__global__ __launch_bounds__(256) void transpose_cvt2_k(
    const float* __restrict__ srcA, const float* __restrict__ srcB, int zSplit,
    u16* __restrict__ dst, int R, int C) {
  __shared__ float tile[64][65];
  int z = blockIdx.z;
  const float* src = (z < zSplit) ? srcA + (size_t)z * R * C
                                  : srcB + (size_t)(z - zSplit) * R * C;
  u16* d = dst + (size_t)z * R * C;
  int c0 = blockIdx.x * 64, r0 = blockIdx.y * 64;
  int tx = threadIdx.x & 15, ty = threadIdx.x >> 4;  // 16 x 16
#pragma unroll
  for (int i = 0; i < 4; i++) {
    float4 v = *(const float4*)(src + (size_t)(r0 + ty + i * 16) * C + c0 + tx * 4);
    tile[ty + i * 16][tx * 4 + 0] = v.x;
    tile[ty + i * 16][tx * 4 + 1] = v.y;
    tile[ty + i * 16][tx * 4 + 2] = v.z;
    tile[ty + i * 16][tx * 4 + 3] = v.w;
  }
  __syncthreads();
  int wx = threadIdx.x & 7, wy = threadIdx.x >> 3;   // 8 x 32
#pragma unroll
  for (int i = 0; i < 2; i++) {
    int cc = wy + i * 32;
    union { u16 h[8]; uint4 u; } o;
#pragma unroll
    for (int j = 0; j < 8; j++) o.h[j] = f2b(tile[wx * 8 + j][cc]);
    *(uint4*)(d + (size_t)(c0 + cc) * R + r0 + wx * 8) = o.u;
  }
}

// ---------- 256x256 BK=64 8-wave grouped GEMM, m201-style 8-phase ----------
// (unchanged from round 4 - verified schedule, 562 TF vs m248 same-shape 848)
// MODE 0: gelu -> bf16 store to C16
// MODE 2: atomic f32: Cf[rowtok[row]*N+col] += rww[row]*v  (skip rowtok<0)
template <int MODE>
__global__ __launch_bounds__(512, 2) void gemm256(
    const u16* __restrict__ A, const u16* __restrict__ Bt,
    u16* __restrict__ C16, float* __restrict__ Cf,
    int N, int K, const int* __restrict__ blk_e, const int* __restrict__ meta,
    size_t bstride, const int* __restrict__ gatherA,
    const int* __restrict__ rowtok, const float* __restrict__ rww) {
  // ---- bijective XCD-chunked swizzle (m204 formula) ----
  const int nwg = gridDim.x * gridDim.y;
  const int bid = blockIdx.y * gridDim.x + blockIdx.x;
  const int q = nwg >> 3, r8 = nwg & 7;
  const int xcd = bid & 7, idx = bid >> 3;
  const int swz = (xcd < r8) ? xcd * (q + 1) + idx
                             : r8 * (q + 1) + (xcd - r8) * q + idx;
  const int bx = swz % gridDim.x, by = swz / gridDim.x;

  const int m0 = by * 256, n0 = bx * 256;
  if (m0 >= meta[0]) return;
  Bt += (size_t)blk_e[by] * bstride;

  __shared__ u16 sm[4][16384];  // A0,B0,A1,B1 : 32 KiB each = 128 KiB
  u16* A0l = &sm[0][0]; u16* B0l = &sm[1][0];
  u16* A1l = &sm[2][0]; u16* B1l = &sm[3][0];

  const int tid = threadIdx.x;
  const int wave = tid >> 6, lane = tid & 63;
  const int wm = wave >> 2, wn = wave & 3;   // 2 x 4 wave grid
  const int fr = lane & 15, hi = lane >> 4;

  // staging sources: unit (h,u): physical slot c=u*512+tid of half h covers
  // row h*128+(c>>3); it fetches LOGICAL 16B slot (c&7)^((c>>3)&7) (XOR swizzle
  // on the global side because global_load_lds writes LDS linearly).
  const u16* aps[2][2];
  const u16* bps[2][2];
#pragma unroll
  for (int h = 0; h < 2; h++)
#pragma unroll
    for (int u = 0; u < 2; u++) {
      int c = u * 512 + tid;
      int rh = c >> 3;
      int sl = (c & 7) ^ (rh & 7);
      int row = h * 128 + rh;
      int ga = m0 + row;
      if (gatherA) { int t2 = gatherA[ga]; ga = (t2 < 0 || t2 >= T_TOK) ? 0 : t2; }
      aps[h][u] = A + (size_t)ga * K + sl * 8;
      bps[h][u] = Bt + (size_t)(n0 + row) * K + sl * 8;
    }

  // stage half h of a [256][64] tile into LDS buffer DL at k-offset KO (2 loads)
#define STG(ps, h, DL, KO)                                                     \
  do {                                                                         \
    GLD16(ps[h][0] + (KO), (DL) + (h) * 8192 + wave * 512);                    \
    GLD16(ps[h][1] + (KO), (DL) + (h) * 8192 + 4096 + wave * 512);             \
  } while (0)

  // per-lane ds_read col offsets (swizzled): fragment row r has r&7 == fr&7
  int co[2];
#pragma unroll
  for (int k = 0; k < 2; k++)
    co[k] = fr * 64 + (((k << 2) + hi) ^ (fr & 7)) * 8;
  const int sA = wm * 8192;   // wm*128 rows * 64
  const int sB = wn * 4096;   // wn*64  rows * 64

  floatx4 acc[8][4];
#pragma unroll
  for (int mi = 0; mi < 8; mi++)
#pragma unroll
    for (int ni = 0; ni < 4; ni++) acc[mi][ni] = (floatx4){0.f, 0.f, 0.f, 0.f};

  short8 aF[4][2], bF[4][2];

#define RD_A(AL, mh)                                                           \
  do {                                                                         \
    _Pragma("unroll")                                                          \
    for (int mi = 0; mi < 4; mi++)                                             \
      _Pragma("unroll")                                                        \
      for (int k = 0; k < 2; k++)                                              \
        aF[mi][k] =                                                            \
            *(const short8*)((AL) + sA + ((mh) * 4 + mi) * 1024 + co[k]);      \
  } while (0)
#define RD_B(BL, n0i)                                                          \
  do {                                                                         \
    _Pragma("unroll")                                                          \
    for (int ni = 0; ni < 2; ni++)                                             \
      _Pragma("unroll")                                                        \
      for (int k = 0; k < 2; k++)                                              \
        bF[(n0i) + ni][k] =                                                    \
            *(const short8*)((BL) + sB + ((n0i) + ni) * 1024 + co[k]);         \
  } while (0)

#define MM(mh, nh)                                                             \
  do {                                                                         \
    __builtin_amdgcn_s_setprio(1);                                             \
    _Pragma("unroll")                                                          \
    for (int mi = 0; mi < 4; mi++)                                             \
      _Pragma("unroll")                                                        \
      for (int ni = 0; ni < 2; ni++)                                           \
        _Pragma("unroll")                                                      \
        for (int k = 0; k < 2; k++)                                            \
          acc[(mh) * 4 + mi][(nh) * 2 + ni] =                                  \
              __builtin_amdgcn_mfma_f32_16x16x32_bf16(                         \
                  aF[mi][k], bF[(nh) * 2 + ni][k],                             \
                  acc[(mh) * 4 + mi][(nh) * 2 + ni], 0, 0, 0);                 \
    __builtin_amdgcn_s_setprio(0);                                             \
  } while (0)

#define BAR() __builtin_amdgcn_s_barrier()
#define LGK0() asm volatile("s_waitcnt lgkmcnt(0)" ::: "memory")
#define VMC(n) asm volatile("s_waitcnt vmcnt(" #n ")" ::: "memory")

  // one iteration = 2 K-tiles (t in buf0, t+1 in buf1); STGE=1: prefetch t+2/t+3
#define ITER(STGE, k1, k2, k3)                                                 \
  do {                                                                         \
    /* ph1 */                                                                  \
    RD_A(A0l, 0); RD_B(B0l, 0);                                                \
    STG(aps, 0, A1l, (k1));                                                    \
    BAR(); LGK0(); MM(0, 0); BAR();                                            \
    /* ph2 */                                                                  \
    RD_B(B0l, 2);                                                              \
    STG(aps, 1, A1l, (k1));                                                    \
    BAR(); LGK0(); MM(0, 1); BAR();                                            \
    /* ph3 */                                                                  \
    RD_A(A0l, 1);                                                              \
    if (STGE) STG(bps, 0, B0l, (k2));                                          \
    BAR(); LGK0(); MM(1, 1); BAR();                                            \
    /* ph4 */                                                                  \
    if (STGE) { STG(bps, 1, B0l, (k2)); VMC(4); } else { VMC(0); }             \
    BAR(); LGK0(); MM(1, 0); BAR();                                            \
    /* ph5 */                                                                  \
    RD_A(A1l, 0); RD_B(B1l, 0);                                                \
    if (STGE) STG(aps, 0, A0l, (k2));                                          \
    BAR(); LGK0(); MM(0, 0); BAR();                                            \
    /* ph6 */                                                                  \
    RD_B(B1l, 2);                                                              \
    if (STGE) STG(aps, 1, A0l, (k2));                                          \
    BAR(); LGK0(); MM(0, 1); BAR();                                            \
    /* ph7 */                                                                  \
    RD_A(A1l, 1);                                                              \
    if (STGE) STG(bps, 0, B1l, (k3));                                          \
    BAR(); LGK0(); MM(1, 1); BAR();                                            \
    /* ph8 */                                                                  \
    if (STGE) { STG(bps, 1, B1l, (k3)); VMC(4); }                              \
    BAR(); LGK0(); MM(1, 0); BAR();                                            \
  } while (0)

  const int NT = K >> 6;   // 16 (up) or 32 (down); even
  const int NI = NT >> 1;  // >= 8

  // prologue: tile0 A+B (8 loads), tile1 B (4 loads); keep tile1-B in flight
  STG(aps, 0, A0l, 0); STG(aps, 1, A0l, 0);
  STG(bps, 0, B0l, 0); STG(bps, 1, B0l, 0);
  STG(bps, 0, B1l, 64); STG(bps, 1, B1l, 64);
  VMC(4);
  BAR();

  for (int i = 0; i < NI - 1; ++i) {
    const int t = i << 1;
    ITER(1, (t + 1) << 6, (t + 2) << 6, (t + 3) << 6);
  }
  { // final iteration: only (NT-1).A stages remain (ph1/ph2); drain at ph4
    const int t = (NI - 1) << 1;
    ITER(0, (t + 1) << 6, 0, 0);
  }
#undef ITER
#undef STG
#undef RD_A
#undef RD_B
#undef MM
#undef BAR
#undef LGK0
#undef VMC

  // ---- epilogue: C/D layout col=lane&15, row=(lane>>4)*4+reg ----
#pragma unroll
  for (int mi = 0; mi < 8; mi++)
#pragma unroll
    for (int r = 0; r < 4; r++) {
      int row = m0 + wm * 128 + mi * 16 + hi * 4 + r;
      int tok = 0; float w = 0.f;
      if (MODE == 2) {
        tok = rowtok[row];
        if (tok >= 0) w = rww[row];
      }
#pragma unroll
      for (int ni = 0; ni < 4; ni++) {
        int col = n0 + wn * 64 + ni * 16 + fr;
        float v = acc[mi][ni][r];
        if (MODE == 0) {
          v = 0.5f * v * (1.0f + erff(v * 0.70710678118654752f));
          C16[(size_t)row * N + col] = f2b(v);
        } else {
          if (tok >= 0) atomicAdd(Cf + (size_t)tok * N + col, w * v);
        }
      }
    }
}

extern "C" void kernel_launch(void* const* d_in, const int* in_sizes, int n_in,
                              void* d_out, int out_size, void* d_ws, size_t ws_size,
                              hipStream_t stream) {
  const float* x  = (const float*)d_in[0];
  const float* Wg = (const float*)d_in[1];
  const float* Wu = (const float*)d_in[2];
  const float* Wd = (const float*)d_in[3];
  const float* W1 = (const float*)d_in[4];
  const float* W2 = (const float*)d_in[5];
  float* out = (float*)d_out;

  // ---- workspace layout (~104 MB; Wt reused up->down) ----
  char* ws = (char*)d_ws;
  size_t off = 0;
  auto alloc = [&](size_t b) -> void* {
    void* p = ws + off; off += (b + 255) & ~(size_t)255; return p;
  };
  int*   counts = (int*)alloc(NEXP * 4);
  int*   cursor = (int*)alloc(NEXP * 4);
  int*   meta   = (int*)alloc(2 * 4);
  int*   blk_e  = (int*)alloc(CAP_MBLK * 4);
  int*   topi   = (int*)alloc(T_TOK * 2 * 4);
  float* topw   = (float*)alloc(T_TOK * 2 * 4);
  int*   rowtok = (int*)alloc(CAP_ROWS * 4);
  float* rww    = (float*)alloc(CAP_ROWS * 4);
  u16*   Xb     = (u16*)alloc((size_t)T_TOK * DDIM * 2);                 // 8.4 MB
  u16*   Wt     = (u16*)alloc((size_t)(NEXP + 1) * FDIM * DDIM * 2);     // 37.7 MB
  u16*   Hrg    = (u16*)alloc((size_t)CAP_ROWS * FDIM * 2);              // 57.7 MB
  (void)n_in; (void)in_sizes; (void)out_size;

  if (ws_size < off) {
    fallback_k<<<(T_TOK * DDIM + 255) / 256, 256, 0, stream>>>(out, T_TOK * DDIM);
    return;
  }

  dim3 tb(256);
  // ---- routing (f32 logits: selection must match reference) ----
  hipMemsetAsync(counts, 0, NEXP * 4, stream);
  hipMemsetAsync(rowtok, 0xFF, (size_t)CAP_ROWS * 4, stream);  // -1 pattern
  hipMemsetAsync(out, 0, (size_t)T_TOK * DDIM * 4, stream);
  router_k<<<T_TOK / 4, 256, 0, stream>>>(x, Wg, Xb, topi, topw, counts);
  scan_k<<<1, 64, 0, stream>>>(counts, cursor, blk_e, meta);
  assign_k<<<(T_TOK * 2 + T_TOK) / 256, 256, 0, stream>>>(topi, topw, cursor, meta,
                                                          rowtok, rww);
  // ---- phase up: Hrg = gelu(gather(x) @ Wu[e])  (expert 8 = shared W1) ----
  transpose_cvt2_k<<<dim3(FDIM / 64, DDIM / 64, NEXP + 1), tb, 0, stream>>>(
      Wu, W1, NEXP, Wt, DDIM, FDIM);
  gemm256<0><<<dim3(FDIM / 256, CAP_MBLK), 512, 0, stream>>>(
      Xb, Wt, Hrg, nullptr, FDIM, DDIM, blk_e, meta, (size_t)FDIM * DDIM,
      rowtok, nullptr, nullptr);
  // ---- phase down: out += rww * (Hrg @ Wd[e])  (expert 8 = shared W2, w=1) ----
  transpose_cvt2_k<<<dim3(DDIM / 64, FDIM / 64, NEXP + 1), tb, 0, stream>>>(
      Wd, W2, NEXP, Wt, FDIM, DDIM);
  gemm256<2><<<dim3(DDIM / 256, CAP_MBLK), 512, 0, stream>>>(
      Hrg, Wt, nullptr, out, DDIM, FDIM, blk_e, meta, (size_t)DDIM * FDIM,
      nullptr, rowtok, rww);
}

// Round 6
// 399.853 us; speedup vs baseline: 1.4404x; 1.2573x over previous
//
#include <hip/hip_runtime.h>
#include <hip/hip_bf16.h>
#include <math.h>

typedef __attribute__((ext_vector_type(8))) short short8;
typedef __attribute__((ext_vector_type(4))) float floatx4;
typedef unsigned short u16;
typedef unsigned int u32;

// ---------- bf16 helpers ----------
__device__ __forceinline__ u16 f2b(float f) {
  union { float f; u32 i; } v; v.f = f;
  u32 i = v.i;
  return (u16)((i + 0x7fffu + ((i >> 16) & 1u)) >> 16);  // RNE
}

// ---------- async global->LDS (16B/lane) ----------
#define GLD16(gp, lp)                                                          \
  __builtin_amdgcn_global_load_lds(                                            \
      (__attribute__((address_space(1))) u32*)(gp),                            \
      (__attribute__((address_space(3))) u32*)(lp), 16, 0, 0)

// ---------- constants ----------
#define T_TOK 4096
#define DDIM 1024
#define FDIM 2048
#define NEXP 8
// merged capacity: routed padded-to-256 (max Σceil = 9984) + 4096 shared
#define CAP_ROWS 14080
#define CAP_MBLK 55   // CAP_ROWS/256

// ---------- fallback: ws too small -> sentinel 1e6 (distinguishable) ----------
__global__ void fallback_k(float* out, int n) {
  int i = blockIdx.x * 256 + threadIdx.x;
  if (i < n) out[i] = 1.0e6f;
}

// ---------- router + x cvt fused: 1 token/wave, no global atomics ----------
__global__ __launch_bounds__(256) void router_k(const float* __restrict__ x,
                                                const float* __restrict__ Wg,
                                                u16* __restrict__ xb,
                                                int* topi, float* topw) {
  __shared__ float wgl[NEXP * DDIM];  // 32 KB, [e][d]
  const int tid = threadIdx.x;
#pragma unroll
  for (int k = 0; k < (NEXP * DDIM) / 256; k++) {
    int i = tid + k * 256;          // coalesced flat read of Wg [d][e]
    wgl[(i & 7) * DDIM + (i >> 3)] = Wg[i];
  }
  __syncthreads();
  const int wave = tid >> 6, lane = tid & 63;
  const int t = blockIdx.x * 4 + wave;
  const float* xr = x + (size_t)t * DDIM;
  u16* xbr = xb + (size_t)t * DDIM;
  float p[NEXP];
#pragma unroll
  for (int e = 0; e < NEXP; e++) p[e] = 0.f;
#pragma unroll
  for (int i = 0; i < 4; i++) {
    int d0 = i * 256 + lane * 4;
    float4 xv = *(const float4*)(xr + d0);
    union { u16 h[4]; uint2 u; } o;
    o.h[0] = f2b(xv.x); o.h[1] = f2b(xv.y); o.h[2] = f2b(xv.z); o.h[3] = f2b(xv.w);
    *(uint2*)(xbr + d0) = o.u;
#pragma unroll
    for (int e = 0; e < NEXP; e++) {
      float4 wv = *(const float4*)(wgl + e * DDIM + d0);
      p[e] += xv.x * wv.x + xv.y * wv.y + xv.z * wv.z + xv.w * wv.w;
    }
  }
#pragma unroll
  for (int off = 32; off > 0; off >>= 1)
#pragma unroll
    for (int e = 0; e < NEXP; e++) p[e] += __shfl_xor(p[e], off);
  if (lane == 0) {
    int i0 = 0; float l0 = p[0];
    for (int e = 1; e < NEXP; e++) if (p[e] > l0) { l0 = p[e]; i0 = e; }
    int i1 = (i0 == 0) ? 1 : 0; float l1 = p[i1];
    for (int e = 0; e < NEXP; e++) if (e != i0 && p[e] > l1) { l1 = p[e]; i1 = e; }
    float e1 = expf(l1 - l0);
    float s = 1.0f + e1;
    topi[t * 2] = i0; topi[t * 2 + 1] = i1;
    topw[t * 2] = 1.0f / s; topw[t * 2 + 1] = e1 / s;
  }
}

// ---------- plan: histogram + prefix + stable partition, one block ----------
// Replaces scan_k + assign_k + counts/rowtok memsets + router atomics.
// Deterministic placement: assignment i -> soff[e] + (#earlier i' with e'==e).
__global__ __launch_bounds__(256) void plan_k(const int* __restrict__ topi,
                                              const float* __restrict__ topw,
                                              int* blk_e, int* meta,
                                              int* rowtok, float* rww) {
  __shared__ int hist[256 * NEXP];   // [tid][e] counts -> exclusive offsets
  __shared__ int tot[NEXP];
  __shared__ int soff[NEXP + 1];
  const int tid = threadIdx.x;
  int e8[32];
  int cnt[NEXP];
#pragma unroll
  for (int e = 0; e < NEXP; e++) cnt[e] = 0;
#pragma unroll
  for (int j = 0; j < 32; j++) {
    int e = topi[tid * 32 + j];
    if (e < 0) e = 0; if (e >= NEXP) e = NEXP - 1;
    e8[j] = e; cnt[e]++;
  }
#pragma unroll
  for (int e = 0; e < NEXP; e++) hist[tid * NEXP + e] = cnt[e];
  __syncthreads();
  if (tid < NEXP) {            // per-expert totals
    int s = 0;
    for (int t = 0; t < 256; t++) s += hist[t * NEXP + tid];
    tot[tid] = s;
  }
  __syncthreads();
  if (tid == 0) {              // segment offsets (pad each expert to 256)
    int off = 0;
    for (int e = 0; e < NEXP; e++) {
      soff[e] = off;
      off += ((tot[e] + 255) >> 8) << 8;
    }
    if (off > CAP_ROWS - 4096) off = CAP_ROWS - 4096;  // defensive (max is exact)
    soff[NEXP] = off;
    meta[1] = off; meta[0] = off + 4096;
  }
  __syncthreads();
  if (tid < NEXP) {            // exclusive prefix across threads, expert `tid`
    int run = soff[tid];
    for (int t = 0; t < 256; t++) {
      int c = hist[t * NEXP + tid];
      hist[t * NEXP + tid] = run;
      run += c;
    }
  }
  const int m1 = soff[NEXP];
  for (int r = tid; r < m1; r += 256) rowtok[r] = -1;   // pad-init routed region
  __syncthreads();
  int off8[NEXP];
#pragma unroll
  for (int e = 0; e < NEXP; e++) off8[e] = hist[tid * NEXP + e];
#pragma unroll
  for (int j = 0; j < 32; j++) {
    int i = tid * 32 + j;
    int e = e8[j];
    int r = off8[e]++;
    rowtok[r] = i >> 1;
    rww[r] = topw[i];
  }
  for (int t = tid; t < T_TOK; t += 256) {              // shared segment
    rowtok[m1 + t] = t;
    rww[m1 + t] = 1.0f;
  }
  if (tid < CAP_MBLK) {
    int r = tid << 8;
    int e;
    if (r >= m1) e = NEXP;
    else {
      e = 0;
      for (int k = 0; k < NEXP; k++) if (r >= soff[k + 1]) e = k + 1;
      if (e > NEXP - 1) e = NEXP - 1;
    }
    blk_e[tid] = e;
  }
}

// ---------- transpose+convert: 64x64 tiles, 16B coalesced both sides --------
__device__ __forceinline__ void tr_body(const float* __restrict__ src,
                                        u16* __restrict__ d, int R, int C) {
  __shared__ float tile[64][65];
  int c0 = blockIdx.x * 64, r0 = blockIdx.y * 64;
  if (c0 >= C || r0 >= R) return;
  int tx = threadIdx.x & 15, ty = threadIdx.x >> 4;  // 16 x 16
#pragma unroll
  for (int i = 0; i < 4; i++) {
    float4 v = *(const float4*)(src + (size_t)(r0 + ty + i * 16) * C + c0 + tx * 4);
    tile[ty + i * 16][tx * 4 + 0] = v.x;
    tile[ty + i * 16][tx * 4 + 1] = v.y;
    tile[ty + i * 16][tx * 4 + 2] = v.z;
    tile[ty + i * 16][tx * 4 + 3] = v.w;
  }
  __syncthreads();
  int wx = threadIdx.x & 7, wy = threadIdx.x >> 3;   // 8 x 32
#pragma unroll
  for (int i = 0; i < 2; i++) {
    int cc = wy + i * 32;
    union { u16 h[8]; uint4 u; } o;
#pragma unroll
    for (int j = 0; j < 8; j++) o.h[j] = f2b(tile[wx * 8 + j][cc]);
    *(uint4*)(d + (size_t)(c0 + cc) * R + r0 + wx * 8) = o.u;
  }
}

// two sources merged on z (fallback path, one phase at a time)
__global__ __launch_bounds__(256) void transpose_cvt2_k(
    const float* __restrict__ srcA, const float* __restrict__ srcB, int zSplit,
    u16* __restrict__ dst, int R, int C) {
  int z = blockIdx.z;
  const float* src = (z < zSplit) ? srcA + (size_t)z * R * C
                                  : srcB + (size_t)(z - zSplit) * R * C;
  tr_body(src, dst + (size_t)z * R * C, R, C);
}

// all 18 weight matrices in ONE dispatch (big-ws path)
__global__ __launch_bounds__(256) void transpose_all_k(
    const float* __restrict__ Wu, const float* __restrict__ W1,
    const float* __restrict__ Wd, const float* __restrict__ W2,
    u16* __restrict__ WtU, u16* __restrict__ WtD) {
  int z = blockIdx.z;
  if (z < NEXP + 1) {
    const int R = DDIM, C = FDIM;
    const float* src = (z < NEXP) ? Wu + (size_t)z * R * C : W1;
    tr_body(src, WtU + (size_t)z * R * C, R, C);
  } else {
    const int R = FDIM, C = DDIM;
    int z2 = z - (NEXP + 1);
    const float* src = (z2 < NEXP) ? Wd + (size_t)z2 * R * C : W2;
    tr_body(src, WtD + (size_t)z2 * R * C, R, C);
  }
}

// ---------- 256x256 BK=64 8-wave grouped GEMM, m201-style 8-phase ----------
// (unchanged - verified schedule; 1 block/CU @128KB LDS)
// MODE 0: gelu -> bf16 store to C16
// MODE 2: atomic f32: Cf[rowtok[row]*N+col] += rww[row]*v  (skip rowtok<0)
template <int MODE>
__global__ __launch_bounds__(512, 2) void gemm256(
    const u16* __restrict__ A, const u16* __restrict__ Bt,
    u16* __restrict__ C16, float* __restrict__ Cf,
    int N, int K, const int* __restrict__ blk_e, const int* __restrict__ meta,
    size_t bstride, const int* __restrict__ gatherA,
    const int* __restrict__ rowtok, const float* __restrict__ rww) {
  // ---- bijective XCD-chunked swizzle (m204 formula) ----
  const int nwg = gridDim.x * gridDim.y;
  const int bid = blockIdx.y * gridDim.x + blockIdx.x;
  const int q = nwg >> 3, r8 = nwg & 7;
  const int xcd = bid & 7, idx = bid >> 3;
  const int swz = (xcd < r8) ? xcd * (q + 1) + idx
                             : r8 * (q + 1) + (xcd - r8) * q + idx;
  const int bx = swz % gridDim.x, by = swz / gridDim.x;

  const int m0 = by * 256, n0 = bx * 256;
  if (m0 >= meta[0]) return;
  Bt += (size_t)blk_e[by] * bstride;

  __shared__ u16 sm[4][16384];  // A0,B0,A1,B1 : 32 KiB each = 128 KiB
  u16* A0l = &sm[0][0]; u16* B0l = &sm[1][0];
  u16* A1l = &sm[2][0]; u16* B1l = &sm[3][0];

  const int tid = threadIdx.x;
  const int wave = tid >> 6, lane = tid & 63;
  const int wm = wave >> 2, wn = wave & 3;   // 2 x 4 wave grid
  const int fr = lane & 15, hi = lane >> 4;

  // staging sources: unit (h,u): physical slot c=u*512+tid of half h covers
  // row h*128+(c>>3); it fetches LOGICAL 16B slot (c&7)^((c>>3)&7) (XOR swizzle
  // on the global side because global_load_lds writes LDS linearly).
  const u16* aps[2][2];
  const u16* bps[2][2];
#pragma unroll
  for (int h = 0; h < 2; h++)
#pragma unroll
    for (int u = 0; u < 2; u++) {
      int c = u * 512 + tid;
      int rh = c >> 3;
      int sl = (c & 7) ^ (rh & 7);
      int row = h * 128 + rh;
      int ga = m0 + row;
      if (gatherA) { int t2 = gatherA[ga]; ga = (t2 < 0 || t2 >= T_TOK) ? 0 : t2; }
      aps[h][u] = A + (size_t)ga * K + sl * 8;
      bps[h][u] = Bt + (size_t)(n0 + row) * K + sl * 8;
    }

  // stage half h of a [256][64] tile into LDS buffer DL at k-offset KO (2 loads)
#define STG(ps, h, DL, KO)                                                     \
  do {                                                                         \
    GLD16(ps[h][0] + (KO), (DL) + (h) * 8192 + wave * 512);                    \
    GLD16(ps[h][1] + (KO), (DL) + (h) * 8192 + 4096 + wave * 512);             \
  } while (0)

  // per-lane ds_read col offsets (swizzled): fragment row r has r&7 == fr&7
  int co[2];
#pragma unroll
  for (int k = 0; k < 2; k++)
    co[k] = fr * 64 + (((k << 2) + hi) ^ (fr & 7)) * 8;
  const int sA = wm * 8192;   // wm*128 rows * 64
  const int sB = wn * 4096;   // wn*64  rows * 64

  floatx4 acc[8][4];
#pragma unroll
  for (int mi = 0; mi < 8; mi++)
#pragma unroll
    for (int ni = 0; ni < 4; ni++) acc[mi][ni] = (floatx4){0.f, 0.f, 0.f, 0.f};

  short8 aF[4][2], bF[4][2];

#define RD_A(AL, mh)                                                           \
  do {                                                                         \
    _Pragma("unroll")                                                          \
    for (int mi = 0; mi < 4; mi++)                                             \
      _Pragma("unroll")                                                        \
      for (int k = 0; k < 2; k++)                                              \
        aF[mi][k] =                                                            \
            *(const short8*)((AL) + sA + ((mh) * 4 + mi) * 1024 + co[k]);      \
  } while (0)
#define RD_B(BL, n0i)                                                          \
  do {                                                                         \
    _Pragma("unroll")                                                          \
    for (int ni = 0; ni < 2; ni++)                                             \
      _Pragma("unroll")                                                        \
      for (int k = 0; k < 2; k++)                                              \
        bF[(n0i) + ni][k] =                                                    \
            *(const short8*)((BL) + sB + ((n0i) + ni) * 1024 + co[k]);         \
  } while (0)

#define MM(mh, nh)                                                             \
  do {                                                                         \
    __builtin_amdgcn_s_setprio(1);                                             \
    _Pragma("unroll")                                                          \
    for (int mi = 0; mi < 4; mi++)                                             \
      _Pragma("unroll")                                                        \
      for (int ni = 0; ni < 2; ni++)                                           \
        _Pragma("unroll")                                                      \
        for (int k = 0; k < 2; k++)                                            \
          acc[(mh) * 4 + mi][(nh) * 2 + ni] =                                  \
              __builtin_amdgcn_mfma_f32_16x16x32_bf16(                         \
                  aF[mi][k], bF[(nh) * 2 + ni][k],                             \
                  acc[(mh) * 4 + mi][(nh) * 2 + ni], 0, 0, 0);                 \
    __builtin_amdgcn_s_setprio(0);                                             \
  } while (0)

#define BAR() __builtin_amdgcn_s_barrier()
#define LGK0() asm volatile("s_waitcnt lgkmcnt(0)" ::: "memory")
#define VMC(n) asm volatile("s_waitcnt vmcnt(" #n ")" ::: "memory")

  // one iteration = 2 K-tiles (t in buf0, t+1 in buf1); STGE=1: prefetch t+2/t+3
#define ITER(STGE, k1, k2, k3)                                                 \
  do {                                                                         \
    /* ph1 */                                                                  \
    RD_A(A0l, 0); RD_B(B0l, 0);                                                \
    STG(aps, 0, A1l, (k1));                                                    \
    BAR(); LGK0(); MM(0, 0); BAR();                                            \
    /* ph2 */                                                                  \
    RD_B(B0l, 2);                                                              \
    STG(aps, 1, A1l, (k1));                                                    \
    BAR(); LGK0(); MM(0, 1); BAR();                                            \
    /* ph3 */                                                                  \
    RD_A(A0l, 1);                                                              \
    if (STGE) STG(bps, 0, B0l, (k2));                                          \
    BAR(); LGK0(); MM(1, 1); BAR();                                            \
    /* ph4 */                                                                  \
    if (STGE) { STG(bps, 1, B0l, (k2)); VMC(4); } else { VMC(0); }             \
    BAR(); LGK0(); MM(1, 0); BAR();                                            \
    /* ph5 */                                                                  \
    RD_A(A1l, 0); RD_B(B1l, 0);                                                \
    if (STGE) STG(aps, 0, A0l, (k2));                                          \
    BAR(); LGK0(); MM(0, 0); BAR();                                            \
    /* ph6 */                                                                  \
    RD_B(B1l, 2);                                                              \
    if (STGE) STG(aps, 1, A0l, (k2));                                          \
    BAR(); LGK0(); MM(0, 1); BAR();                                            \
    /* ph7 */                                                                  \
    RD_A(A1l, 1);                                                              \
    if (STGE) STG(bps, 0, B1l, (k3));                                          \
    BAR(); LGK0(); MM(1, 1); BAR();                                            \
    /* ph8 */                                                                  \
    if (STGE) { STG(bps, 1, B1l, (k3)); VMC(4); }                              \
    BAR(); LGK0(); MM(1, 0); BAR();                                            \
  } while (0)

  const int NT = K >> 6;   // 16 (up) or 32 (down); even
  const int NI = NT >> 1;  // >= 8

  // prologue: tile0 A+B (8 loads), tile1 B (4 loads); keep tile1-B in flight
  STG(aps, 0, A0l, 0); STG(aps, 1, A0l, 0);
  STG(bps, 0, B0l, 0); STG(bps, 1, B0l, 0);
  STG(bps, 0, B1l, 64); STG(bps, 1, B1l, 64);
  VMC(4);
  BAR();

  for (int i = 0; i < NI - 1; ++i) {
    const int t = i << 1;
    ITER(1, (t + 1) << 6, (t + 2) << 6, (t + 3) << 6);
  }
  { // final iteration: only (NT-1).A stages remain (ph1/ph2); drain at ph4
    const int t = (NI - 1) << 1;
    ITER(0, (t + 1) << 6, 0, 0);
  }
#undef ITER
#undef STG
#undef RD_A
#undef RD_B
#undef MM
#undef BAR
#undef LGK0
#undef VMC

  // ---- epilogue: C/D layout col=lane&15, row=(lane>>4)*4+reg ----
#pragma unroll
  for (int mi = 0; mi < 8; mi++)
#pragma unroll
    for (int r = 0; r < 4; r++) {
      int row = m0 + wm * 128 + mi * 16 + hi * 4 + r;
      int tok = 0; float w = 0.f;
      if (MODE == 2) {
        tok = rowtok[row];
        if (tok >= 0) w = rww[row];
      }
#pragma unroll
      for (int ni = 0; ni < 4; ni++) {
        int col = n0 + wn * 64 + ni * 16 + fr;
        float v = acc[mi][ni][r];
        if (MODE == 0) {
          v = 0.5f * v * (1.0f + erff(v * 0.70710678118654752f));
          C16[(size_t)row * N + col] = f2b(v);
        } else {
          if (tok >= 0) atomicAdd(Cf + (size_t)tok * N + col, w * v);
        }
      }
    }
}

extern "C" void kernel_launch(void* const* d_in, const int* in_sizes, int n_in,
                              void* d_out, int out_size, void* d_ws, size_t ws_size,
                              hipStream_t stream) {
  const float* x  = (const float*)d_in[0];
  const float* Wg = (const float*)d_in[1];
  const float* Wu = (const float*)d_in[2];
  const float* Wd = (const float*)d_in[3];
  const float* W1 = (const float*)d_in[4];
  const float* W2 = (const float*)d_in[5];
  float* out = (float*)d_out;

  // ---- workspace layout (base ~104 MB; +37.7 MB WtD if ws allows) ----
  char* ws = (char*)d_ws;
  size_t off = 0;
  auto alloc = [&](size_t b) -> void* {
    void* p = ws + off; off += (b + 255) & ~(size_t)255; return p;
  };
  int*   meta   = (int*)alloc(2 * 4);
  int*   blk_e  = (int*)alloc(CAP_MBLK * 4);
  int*   topi   = (int*)alloc(T_TOK * 2 * 4);
  float* topw   = (float*)alloc(T_TOK * 2 * 4);
  int*   rowtok = (int*)alloc(CAP_ROWS * 4);
  float* rww    = (float*)alloc(CAP_ROWS * 4);
  u16*   Xb     = (u16*)alloc((size_t)T_TOK * DDIM * 2);                 // 8.4 MB
  u16*   Wt     = (u16*)alloc((size_t)(NEXP + 1) * FDIM * DDIM * 2);     // 37.7 MB
  u16*   Hrg    = (u16*)alloc((size_t)CAP_ROWS * FDIM * 2);              // 57.7 MB
  const size_t off_base = off;
  u16*   WtD    = (u16*)alloc((size_t)(NEXP + 1) * FDIM * DDIM * 2);     // +37.7 MB
  const bool haveWtD = (ws_size >= off);
  (void)n_in; (void)in_sizes; (void)out_size;

  if (ws_size < off_base) {
    fallback_k<<<(T_TOK * DDIM + 255) / 256, 256, 0, stream>>>(out, T_TOK * DDIM);
    return;
  }

  // ---- routing (f32 logits: selection must match reference) ----
  hipMemsetAsync(out, 0, (size_t)T_TOK * DDIM * 4, stream);
  router_k<<<T_TOK / 4, 256, 0, stream>>>(x, Wg, Xb, topi, topw);
  plan_k<<<1, 256, 0, stream>>>(topi, topw, blk_e, meta, rowtok, rww);

  if (haveWtD) {
    // single transpose dispatch for all 18 weight matrices
    transpose_all_k<<<dim3(FDIM / 64, FDIM / 64, 2 * (NEXP + 1)), 256, 0, stream>>>(
        Wu, W1, Wd, W2, Wt, WtD);
    gemm256<0><<<dim3(FDIM / 256, CAP_MBLK), 512, 0, stream>>>(
        Xb, Wt, Hrg, nullptr, FDIM, DDIM, blk_e, meta, (size_t)FDIM * DDIM,
        rowtok, nullptr, nullptr);
    gemm256<2><<<dim3(DDIM / 256, CAP_MBLK), 512, 0, stream>>>(
        Hrg, WtD, nullptr, out, DDIM, FDIM, blk_e, meta, (size_t)DDIM * FDIM,
        nullptr, rowtok, rww);
  } else {
    transpose_cvt2_k<<<dim3(FDIM / 64, DDIM / 64, NEXP + 1), 256, 0, stream>>>(
        Wu, W1, NEXP, Wt, DDIM, FDIM);
    gemm256<0><<<dim3(FDIM / 256, CAP_MBLK), 512, 0, stream>>>(
        Xb, Wt, Hrg, nullptr, FDIM, DDIM, blk_e, meta, (size_t)FDIM * DDIM,
        rowtok, nullptr, nullptr);
    transpose_cvt2_k<<<dim3(DDIM / 64, FDIM / 64, NEXP + 1), 256, 0, stream>>>(
        Wd, W2, NEXP, Wt, FDIM, DDIM);
    gemm256<2><<<dim3(DDIM / 256, CAP_MBLK), 512, 0, stream>>>(
        Hrg, Wt, nullptr, out, DDIM, FDIM, blk_e, meta, (size_t)DDIM * FDIM,
        nullptr, rowtok, rww);
  }
}

// Round 7
// 388.349 us; speedup vs baseline: 1.4831x; 1.0296x over previous
//
#include <hip/hip_runtime.h>
#include <hip/hip_bf16.h>
#include <math.h>

typedef __attribute__((ext_vector_type(8))) short short8;
typedef __attribute__((ext_vector_type(4))) float floatx4;
typedef unsigned short u16;
typedef unsigned int u32;

// ---------- bf16 helpers ----------
__device__ __forceinline__ u16 f2b(float f) {
  union { float f; u32 i; } v; v.f = f;
  u32 i = v.i;
  return (u16)((i + 0x7fffu + ((i >> 16) & 1u)) >> 16);  // RNE
}

// ---------- async global->LDS (16B/lane) ----------
#define GLD16(gp, lp)                                                          \
  __builtin_amdgcn_global_load_lds(                                            \
      (__attribute__((address_space(1))) u32*)(gp),                            \
      (__attribute__((address_space(3))) u32*)(lp), 16, 0, 0)

// ---------- constants ----------
#define T_TOK 4096
#define DDIM 1024
#define FDIM 2048
#define NEXP 8
// merged capacity: routed padded-to-256 (max Σceil = 9984) + 4096 shared
#define CAP_ROWS 14080
#define CAP_MBLK 55   // CAP_ROWS/256

// ---------- fallback: ws too small -> sentinel 1e6 (distinguishable) ----------
__global__ void fallback_k(float* out, int n) {
  int i = blockIdx.x * 256 + threadIdx.x;
  if (i < n) out[i] = 1.0e6f;
}

// ---------- router + x cvt + out-zero fused: 1 token/wave ----------
__global__ __launch_bounds__(256) void router_k(const float* __restrict__ x,
                                                const float* __restrict__ Wg,
                                                u16* __restrict__ xb,
                                                int* topi, float* topw,
                                                float* __restrict__ out) {
  __shared__ float wgl[NEXP * DDIM];  // 32 KB, [e][d]
  const int tid = threadIdx.x;
  // zero the output rows owned by this block (removes a memset dispatch)
  {
    const float4 z4 = make_float4(0.f, 0.f, 0.f, 0.f);
    float* ob = out + (size_t)blockIdx.x * 4 * DDIM;
#pragma unroll
    for (int i = 0; i < 4; i++)
      *(float4*)(ob + (tid + i * 256) * 4) = z4;
  }
#pragma unroll
  for (int k = 0; k < (NEXP * DDIM) / 256; k++) {
    int i = tid + k * 256;          // coalesced flat read of Wg [d][e]
    wgl[(i & 7) * DDIM + (i >> 3)] = Wg[i];
  }
  __syncthreads();
  const int wave = tid >> 6, lane = tid & 63;
  const int t = blockIdx.x * 4 + wave;
  const float* xr = x + (size_t)t * DDIM;
  u16* xbr = xb + (size_t)t * DDIM;
  float p[NEXP];
#pragma unroll
  for (int e = 0; e < NEXP; e++) p[e] = 0.f;
#pragma unroll
  for (int i = 0; i < 4; i++) {
    int d0 = i * 256 + lane * 4;
    float4 xv = *(const float4*)(xr + d0);
    union { u16 h[4]; uint2 u; } o;
    o.h[0] = f2b(xv.x); o.h[1] = f2b(xv.y); o.h[2] = f2b(xv.z); o.h[3] = f2b(xv.w);
    *(uint2*)(xbr + d0) = o.u;
#pragma unroll
    for (int e = 0; e < NEXP; e++) {
      float4 wv = *(const float4*)(wgl + e * DDIM + d0);
      p[e] += xv.x * wv.x + xv.y * wv.y + xv.z * wv.z + xv.w * wv.w;
    }
  }
#pragma unroll
  for (int off = 32; off > 0; off >>= 1)
#pragma unroll
    for (int e = 0; e < NEXP; e++) p[e] += __shfl_xor(p[e], off);
  if (lane == 0) {
    int i0 = 0; float l0 = p[0];
    for (int e = 1; e < NEXP; e++) if (p[e] > l0) { l0 = p[e]; i0 = e; }
    int i1 = (i0 == 0) ? 1 : 0; float l1 = p[i1];
    for (int e = 0; e < NEXP; e++) if (e != i0 && p[e] > l1) { l1 = p[e]; i1 = e; }
    float e1 = expf(l1 - l0);
    float s = 1.0f + e1;
    topi[t * 2] = i0; topi[t * 2 + 1] = i1;
    topw[t * 2] = 1.0f / s; topw[t * 2 + 1] = e1 / s;
  }
}

// ---------- plan body: histogram + prefix + stable partition (256 thr) -------
// Deterministic placement: assignment i -> soff[e] + (#earlier i' with e'==e).
__device__ __forceinline__ void plan_body(const int* __restrict__ topi,
                                          const float* __restrict__ topw,
                                          int* blk_e, int* meta,
                                          int* rowtok, float* rww,
                                          int* hist, int* tot, int* soff) {
  const int tid = threadIdx.x;
  int e8[32];
  int cnt[NEXP];
#pragma unroll
  for (int e = 0; e < NEXP; e++) cnt[e] = 0;
#pragma unroll
  for (int j = 0; j < 32; j++) {
    int e = topi[tid * 32 + j];
    if (e < 0) e = 0; if (e >= NEXP) e = NEXP - 1;
    e8[j] = e; cnt[e]++;
  }
#pragma unroll
  for (int e = 0; e < NEXP; e++) hist[tid * NEXP + e] = cnt[e];
  __syncthreads();
  if (tid < NEXP) {            // per-expert totals
    int s = 0;
    for (int t = 0; t < 256; t++) s += hist[t * NEXP + tid];
    tot[tid] = s;
  }
  __syncthreads();
  if (tid == 0) {              // segment offsets (pad each expert to 256)
    int off = 0;
    for (int e = 0; e < NEXP; e++) {
      soff[e] = off;
      off += ((tot[e] + 255) >> 8) << 8;
    }
    if (off > CAP_ROWS - 4096) off = CAP_ROWS - 4096;  // defensive (max is exact)
    soff[NEXP] = off;
    meta[1] = off; meta[0] = off + 4096;
  }
  __syncthreads();
  if (tid < NEXP) {            // exclusive prefix across threads, expert `tid`
    int run = soff[tid];
    for (int t = 0; t < 256; t++) {
      int c = hist[t * NEXP + tid];
      hist[t * NEXP + tid] = run;
      run += c;
    }
  }
  const int m1 = soff[NEXP];
  for (int r = tid; r < m1; r += 256) rowtok[r] = -1;   // pad-init routed region
  __syncthreads();
  int off8[NEXP];
#pragma unroll
  for (int e = 0; e < NEXP; e++) off8[e] = hist[tid * NEXP + e];
#pragma unroll
  for (int j = 0; j < 32; j++) {
    int i = tid * 32 + j;
    int e = e8[j];
    int r = off8[e]++;
    rowtok[r] = i >> 1;
    rww[r] = topw[i];
  }
  for (int t = tid; t < T_TOK; t += 256) {              // shared segment
    rowtok[m1 + t] = t;
    rww[m1 + t] = 1.0f;
  }
  if (tid < CAP_MBLK) {
    int r = tid << 8;
    int e;
    if (r >= m1) e = NEXP;
    else {
      e = 0;
      for (int k = 0; k < NEXP; k++) if (r >= soff[k + 1]) e = k + 1;
      if (e > NEXP - 1) e = NEXP - 1;
    }
    blk_e[tid] = e;
  }
}

// standalone plan kernel (fallback path only)
__global__ __launch_bounds__(256) void plan_k(const int* __restrict__ topi,
                                              const float* __restrict__ topw,
                                              int* blk_e, int* meta,
                                              int* rowtok, float* rww) {
  __shared__ int hist[256 * NEXP];
  __shared__ int tot[NEXP];
  __shared__ int soff[NEXP + 1];
  plan_body(topi, topw, blk_e, meta, rowtok, rww, hist, tot, soff);
}

// ---------- transpose+convert body: 64x64 tiles, 16B coalesced both sides ---
__device__ __forceinline__ void tr_body(const float* __restrict__ src,
                                        u16* __restrict__ d, int R, int C,
                                        float (*tile)[65]) {
  int c0 = blockIdx.x * 64, r0 = blockIdx.y * 64;
  if (c0 >= C || r0 >= R) return;
  int tx = threadIdx.x & 15, ty = threadIdx.x >> 4;  // 16 x 16
#pragma unroll
  for (int i = 0; i < 4; i++) {
    float4 v = *(const float4*)(src + (size_t)(r0 + ty + i * 16) * C + c0 + tx * 4);
    tile[ty + i * 16][tx * 4 + 0] = v.x;
    tile[ty + i * 16][tx * 4 + 1] = v.y;
    tile[ty + i * 16][tx * 4 + 2] = v.z;
    tile[ty + i * 16][tx * 4 + 3] = v.w;
  }
  __syncthreads();
  int wx = threadIdx.x & 7, wy = threadIdx.x >> 3;   // 8 x 32
#pragma unroll
  for (int i = 0; i < 2; i++) {
    int cc = wy + i * 32;
    union { u16 h[8]; uint4 u; } o;
#pragma unroll
    for (int j = 0; j < 8; j++) o.h[j] = f2b(tile[wx * 8 + j][cc]);
    *(uint4*)(d + (size_t)(c0 + cc) * R + r0 + wx * 8) = o.u;
  }
}

// two sources merged on z (fallback path, one phase at a time)
__global__ __launch_bounds__(256) void transpose_cvt2_k(
    const float* __restrict__ srcA, const float* __restrict__ srcB, int zSplit,
    u16* __restrict__ dst, int R, int C) {
  __shared__ float tile[64][65];
  int z = blockIdx.z;
  const float* src = (z < zSplit) ? srcA + (size_t)z * R * C
                                  : srcB + (size_t)(z - zSplit) * R * C;
  tr_body(src, dst + (size_t)z * R * C, R, C, tile);
}

// all 18 weight transposes + the routing plan in ONE dispatch (big-ws path):
// z in [0, 9): Wu/W1 -> WtU ; z in [9, 18): Wd/W2 -> WtD ; z == 18: plan block.
__global__ __launch_bounds__(256) void transplan_k(
    const float* __restrict__ Wu, const float* __restrict__ W1,
    const float* __restrict__ Wd, const float* __restrict__ W2,
    u16* __restrict__ WtU, u16* __restrict__ WtD,
    const int* __restrict__ topi, const float* __restrict__ topw,
    int* blk_e, int* meta, int* rowtok, float* rww) {
  __shared__ union {
    float tile[64][65];                                   // 16.6 KB
    struct { int hist[256 * NEXP]; int tot[NEXP]; int soff[NEXP + 1]; } p;
  } sm;
  int z = blockIdx.z;
  if (z < NEXP + 1) {
    const int R = DDIM, C = FDIM;
    const float* src = (z < NEXP) ? Wu + (size_t)z * R * C : W1;
    tr_body(src, WtU + (size_t)z * R * C, R, C, sm.tile);
  } else if (z < 2 * (NEXP + 1)) {
    const int R = FDIM, C = DDIM;
    int z2 = z - (NEXP + 1);
    const float* src = (z2 < NEXP) ? Wd + (size_t)z2 * R * C : W2;
    tr_body(src, WtD + (size_t)z2 * R * C, R, C, sm.tile);
  } else {
    if (blockIdx.x == 0 && blockIdx.y == 0)
      plan_body(topi, topw, blk_e, meta, rowtok, rww, sm.p.hist, sm.p.tot,
                sm.p.soff);
  }
}

// ---------- 256x256 BK=64 8-wave grouped GEMM, m201-style 8-phase ----------
// (unchanged - verified schedule; 1 block/CU @128KB LDS)
// MODE 0: gelu -> bf16 store to C16
// MODE 2: atomic f32: Cf[rowtok[row]*N+col] += rww[row]*v  (skip rowtok<0)
template <int MODE>
__global__ __launch_bounds__(512, 2) void gemm256(
    const u16* __restrict__ A, const u16* __restrict__ Bt,
    u16* __restrict__ C16, float* __restrict__ Cf,
    int N, int K, const int* __restrict__ blk_e, const int* __restrict__ meta,
    size_t bstride, const int* __restrict__ gatherA,
    const int* __restrict__ rowtok, const float* __restrict__ rww) {
  // ---- bijective XCD-chunked swizzle (m204 formula) ----
  const int nwg = gridDim.x * gridDim.y;
  const int bid = blockIdx.y * gridDim.x + blockIdx.x;
  const int q = nwg >> 3, r8 = nwg & 7;
  const int xcd = bid & 7, idx = bid >> 3;
  const int swz = (xcd < r8) ? xcd * (q + 1) + idx
                             : r8 * (q + 1) + (xcd - r8) * q + idx;
  const int bx = swz % gridDim.x, by = swz / gridDim.x;

  const int m0 = by * 256, n0 = bx * 256;
  if (m0 >= meta[0]) return;
  Bt += (size_t)blk_e[by] * bstride;

  __shared__ u16 sm[4][16384];  // A0,B0,A1,B1 : 32 KiB each = 128 KiB
  u16* A0l = &sm[0][0]; u16* B0l = &sm[1][0];
  u16* A1l = &sm[2][0]; u16* B1l = &sm[3][0];

  const int tid = threadIdx.x;
  const int wave = tid >> 6, lane = tid & 63;
  const int wm = wave >> 2, wn = wave & 3;   // 2 x 4 wave grid
  const int fr = lane & 15, hi = lane >> 4;

  // staging sources: unit (h,u): physical slot c=u*512+tid of half h covers
  // row h*128+(c>>3); it fetches LOGICAL 16B slot (c&7)^((c>>3)&7) (XOR swizzle
  // on the global side because global_load_lds writes LDS linearly).
  const u16* aps[2][2];
  const u16* bps[2][2];
#pragma unroll
  for (int h = 0; h < 2; h++)
#pragma unroll
    for (int u = 0; u < 2; u++) {
      int c = u * 512 + tid;
      int rh = c >> 3;
      int sl = (c & 7) ^ (rh & 7);
      int row = h * 128 + rh;
      int ga = m0 + row;
      if (gatherA) { int t2 = gatherA[ga]; ga = (t2 < 0 || t2 >= T_TOK) ? 0 : t2; }
      aps[h][u] = A + (size_t)ga * K + sl * 8;
      bps[h][u] = Bt + (size_t)(n0 + row) * K + sl * 8;
    }

  // stage half h of a [256][64] tile into LDS buffer DL at k-offset KO (2 loads)
#define STG(ps, h, DL, KO)                                                     \
  do {                                                                         \
    GLD16(ps[h][0] + (KO), (DL) + (h) * 8192 + wave * 512);                    \
    GLD16(ps[h][1] + (KO), (DL) + (h) * 8192 + 4096 + wave * 512);             \
  } while (0)

  // per-lane ds_read col offsets (swizzled): fragment row r has r&7 == fr&7
  int co[2];
#pragma unroll
  for (int k = 0; k < 2; k++)
    co[k] = fr * 64 + (((k << 2) + hi) ^ (fr & 7)) * 8;
  const int sA = wm * 8192;   // wm*128 rows * 64
  const int sB = wn * 4096;   // wn*64  rows * 64

  floatx4 acc[8][4];
#pragma unroll
  for (int mi = 0; mi < 8; mi++)
#pragma unroll
    for (int ni = 0; ni < 4; ni++) acc[mi][ni] = (floatx4){0.f, 0.f, 0.f, 0.f};

  short8 aF[4][2], bF[4][2];

#define RD_A(AL, mh)                                                           \
  do {                                                                         \
    _Pragma("unroll")                                                          \
    for (int mi = 0; mi < 4; mi++)                                             \
      _Pragma("unroll")                                                        \
      for (int k = 0; k < 2; k++)                                              \
        aF[mi][k] =                                                            \
            *(const short8*)((AL) + sA + ((mh) * 4 + mi) * 1024 + co[k]);      \
  } while (0)
#define RD_B(BL, n0i)                                                          \
  do {                                                                         \
    _Pragma("unroll")                                                          \
    for (int ni = 0; ni < 2; ni++)                                             \
      _Pragma("unroll")                                                        \
      for (int k = 0; k < 2; k++)                                              \
        bF[(n0i) + ni][k] =                                                    \
            *(const short8*)((BL) + sB + ((n0i) + ni) * 1024 + co[k]);         \
  } while (0)

#define MM(mh, nh)                                                             \
  do {                                                                         \
    __builtin_amdgcn_s_setprio(1);                                             \
    _Pragma("unroll")                                                          \
    for (int mi = 0; mi < 4; mi++)                                             \
      _Pragma("unroll")                                                        \
      for (int ni = 0; ni < 2; ni++)                                           \
        _Pragma("unroll")                                                      \
        for (int k = 0; k < 2; k++)                                            \
          acc[(mh) * 4 + mi][(nh) * 2 + ni] =                                  \
              __builtin_amdgcn_mfma_f32_16x16x32_bf16(                         \
                  aF[mi][k], bF[(nh) * 2 + ni][k],                             \
                  acc[(mh) * 4 + mi][(nh) * 2 + ni], 0, 0, 0);                 \
    __builtin_amdgcn_s_setprio(0);                                             \
  } while (0)

#define BAR() __builtin_amdgcn_s_barrier()
#define LGK0() asm volatile("s_waitcnt lgkmcnt(0)" ::: "memory")
#define VMC(n) asm volatile("s_waitcnt vmcnt(" #n ")" ::: "memory")

  // one iteration = 2 K-tiles (t in buf0, t+1 in buf1); STGE=1: prefetch t+2/t+3
#define ITER(STGE, k1, k2, k3)                                                 \
  do {                                                                         \
    /* ph1 */                                                                  \
    RD_A(A0l, 0); RD_B(B0l, 0);                                                \
    STG(aps, 0, A1l, (k1));                                                    \
    BAR(); LGK0(); MM(0, 0); BAR();                                            \
    /* ph2 */                                                                  \
    RD_B(B0l, 2);                                                              \
    STG(aps, 1, A1l, (k1));                                                    \
    BAR(); LGK0(); MM(0, 1); BAR();                                            \
    /* ph3 */                                                                  \
    RD_A(A0l, 1);                                                              \
    if (STGE) STG(bps, 0, B0l, (k2));                                          \
    BAR(); LGK0(); MM(1, 1); BAR();                                            \
    /* ph4 */                                                                  \
    if (STGE) { STG(bps, 1, B0l, (k2)); VMC(4); } else { VMC(0); }             \
    BAR(); LGK0(); MM(1, 0); BAR();                                            \
    /* ph5 */                                                                  \
    RD_A(A1l, 0); RD_B(B1l, 0);                                                \
    if (STGE) STG(aps, 0, A0l, (k2));                                          \
    BAR(); LGK0(); MM(0, 0); BAR();                                            \
    /* ph6 */                                                                  \
    RD_B(B1l, 2);                                                              \
    if (STGE) STG(aps, 1, A0l, (k2));                                          \
    BAR(); LGK0(); MM(0, 1); BAR();                                            \
    /* ph7 */                                                                  \
    RD_A(A1l, 1);                                                              \
    if (STGE) STG(bps, 0, B1l, (k3));                                          \
    BAR(); LGK0(); MM(1, 1); BAR();                                            \
    /* ph8 */                                                                  \
    if (STGE) { STG(bps, 1, B1l, (k3)); VMC(4); }                              \
    BAR(); LGK0(); MM(1, 0); BAR();                                            \
  } while (0)

  const int NT = K >> 6;   // 16 (up) or 32 (down); even
  const int NI = NT >> 1;  // >= 8

  // prologue: tile0 A+B (8 loads), tile1 B (4 loads); keep tile1-B in flight
  STG(aps, 0, A0l, 0); STG(aps, 1, A0l, 0);
  STG(bps, 0, B0l, 0); STG(bps, 1, B0l, 0);
  STG(bps, 0, B1l, 64); STG(bps, 1, B1l, 64);
  VMC(4);
  BAR();

  for (int i = 0; i < NI - 1; ++i) {
    const int t = i << 1;
    ITER(1, (t + 1) << 6, (t + 2) << 6, (t + 3) << 6);
  }
  { // final iteration: only (NT-1).A stages remain (ph1/ph2); drain at ph4
    const int t = (NI - 1) << 1;
    ITER(0, (t + 1) << 6, 0, 0);
  }
#undef ITER
#undef STG
#undef RD_A
#undef RD_B
#undef MM
#undef BAR
#undef LGK0
#undef VMC

  // ---- epilogue: C/D layout col=lane&15, row=(lane>>4)*4+reg ----
#pragma unroll
  for (int mi = 0; mi < 8; mi++)
#pragma unroll
    for (int r = 0; r < 4; r++) {
      int row = m0 + wm * 128 + mi * 16 + hi * 4 + r;
      int tok = 0; float w = 0.f;
      if (MODE == 2) {
        tok = rowtok[row];
        if (tok >= 0) w = rww[row];
      }
#pragma unroll
      for (int ni = 0; ni < 4; ni++) {
        int col = n0 + wn * 64 + ni * 16 + fr;
        float v = acc[mi][ni][r];
        if (MODE == 0) {
          v = 0.5f * v * (1.0f + erff(v * 0.70710678118654752f));
          C16[(size_t)row * N + col] = f2b(v);
        } else {
          if (tok >= 0) atomicAdd(Cf + (size_t)tok * N + col, w * v);
        }
      }
    }
}

extern "C" void kernel_launch(void* const* d_in, const int* in_sizes, int n_in,
                              void* d_out, int out_size, void* d_ws, size_t ws_size,
                              hipStream_t stream) {
  const float* x  = (const float*)d_in[0];
  const float* Wg = (const float*)d_in[1];
  const float* Wu = (const float*)d_in[2];
  const float* Wd = (const float*)d_in[3];
  const float* W1 = (const float*)d_in[4];
  const float* W2 = (const float*)d_in[5];
  float* out = (float*)d_out;

  // ---- workspace layout (base ~104 MB; +37.7 MB WtD if ws allows) ----
  char* ws = (char*)d_ws;
  size_t off = 0;
  auto alloc = [&](size_t b) -> void* {
    void* p = ws + off; off += (b + 255) & ~(size_t)255; return p;
  };
  int*   meta   = (int*)alloc(2 * 4);
  int*   blk_e  = (int*)alloc(CAP_MBLK * 4);
  int*   topi   = (int*)alloc(T_TOK * 2 * 4);
  float* topw   = (float*)alloc(T_TOK * 2 * 4);
  int*   rowtok = (int*)alloc(CAP_ROWS * 4);
  float* rww    = (float*)alloc(CAP_ROWS * 4);
  u16*   Xb     = (u16*)alloc((size_t)T_TOK * DDIM * 2);                 // 8.4 MB
  u16*   Wt     = (u16*)alloc((size_t)(NEXP + 1) * FDIM * DDIM * 2);     // 37.7 MB
  u16*   Hrg    = (u16*)alloc((size_t)CAP_ROWS * FDIM * 2);              // 57.7 MB
  const size_t off_base = off;
  u16*   WtD    = (u16*)alloc((size_t)(NEXP + 1) * FDIM * DDIM * 2);     // +37.7 MB
  const bool haveWtD = (ws_size >= off);
  (void)n_in; (void)in_sizes; (void)out_size;

  if (ws_size < off_base) {
    fallback_k<<<(T_TOK * DDIM + 255) / 256, 256, 0, stream>>>(out, T_TOK * DDIM);
    return;
  }

  // ---- routing (f32 logits: selection must match reference) ----
  router_k<<<T_TOK / 4, 256, 0, stream>>>(x, Wg, Xb, topi, topw, out);

  if (haveWtD) {
    // 18 weight transposes + routing plan in one dispatch
    transplan_k<<<dim3(FDIM / 64, FDIM / 64, 2 * (NEXP + 1) + 1), 256, 0, stream>>>(
        Wu, W1, Wd, W2, Wt, WtD, topi, topw, blk_e, meta, rowtok, rww);
    gemm256<0><<<dim3(FDIM / 256, CAP_MBLK), 512, 0, stream>>>(
        Xb, Wt, Hrg, nullptr, FDIM, DDIM, blk_e, meta, (size_t)FDIM * DDIM,
        rowtok, nullptr, nullptr);
    gemm256<2><<<dim3(DDIM / 256, CAP_MBLK), 512, 0, stream>>>(
        Hrg, WtD, nullptr, out, DDIM, FDIM, blk_e, meta, (size_t)DDIM * FDIM,
        nullptr, rowtok, rww);
  } else {
    plan_k<<<1, 256, 0, stream>>>(topi, topw, blk_e, meta, rowtok, rww);
    transpose_cvt2_k<<<dim3(FDIM / 64, DDIM / 64, NEXP + 1), 256, 0, stream>>>(
        Wu, W1, NEXP, Wt, DDIM, FDIM);
    gemm256<0><<<dim3(FDIM / 256, CAP_MBLK), 512, 0, stream>>>(
        Xb, Wt, Hrg, nullptr, FDIM, DDIM, blk_e, meta, (size_t)FDIM * DDIM,
        rowtok, nullptr, nullptr);
    transpose_cvt2_k<<<dim3(DDIM / 64, FDIM / 64, NEXP + 1), 256, 0, stream>>>(
        Wd, W2, NEXP, Wt, FDIM, DDIM);
    gemm256<2><<<dim3(DDIM / 256, CAP_MBLK), 512, 0, stream>>>(
        Hrg, Wt, nullptr, out, DDIM, FDIM, blk_e, meta, (size_t)DDIM * FDIM,
        nullptr, rowtok, rww);
  }
}